// Round 1
// baseline (1070.480 us; speedup 1.0000x reference)
//
#include <hip/hip_runtime.h>
#include <math.h>

#define BB 8
#define NN 1024
#define KK 16
#define NKP (NN*KK)
#define BN_INV 0.99999500003749981f   // 1/sqrt(1+1e-5), matches fp32-rounded ref constant

__device__ __forceinline__ float lrelu(float v) { return v >= 0.f ? v : 0.2f * v; }

// ---------------- workspace layout (float offsets) ----------------
constexpr size_t OFF_IDX   = 0;                        // int[B*N*K]
constexpr size_t OFF_X1    = 131072;                   // (B,64,N) ch-major
constexpr size_t OFF_X1P   = OFF_X1   + 524288;        // (B,N,64) point-major
constexpr size_t OFF_X2    = OFF_X1P  + 524288;
constexpr size_t OFF_X2P   = OFF_X2   + 524288;
constexpr size_t OFF_X3    = OFF_X2P  + 524288;        // (B,128,N)
constexpr size_t OFF_X3P   = OFF_X3   + 1048576;
constexpr size_t OFF_X4    = OFF_X3P  + 1048576;       // (B,256,N)
constexpr size_t OFF_PMAX  = OFF_X4   + 2097152;       // (B,16,1024)
constexpr size_t OFF_PSUM  = OFF_PMAX + 131072;
constexpr size_t OFF_XP    = OFF_PSUM + 131072;        // (B,2048)
constexpr size_t OFF_XF1   = OFF_XP   + 16384;         // (B,512)
constexpr size_t OFF_XF2   = OFF_XF1  + 4096;          // (B,256)
constexpr size_t OFF_M1W0T = OFF_XF2  + 2048;          // [6][64]
constexpr size_t OFF_M1WMT = OFF_M1W0T + 384;          // [64][64]
constexpr size_t OFF_M1W1S = OFF_M1WMT + 4096;         // [390][64]
constexpr size_t OFF_M2W0T = OFF_M1W1S + 24960;        // [128][64]
constexpr size_t OFF_M2WMT = OFF_M2W0T + 8192;
constexpr size_t OFF_M2W1S = OFF_M2WMT + 4096;
constexpr size_t OFF_W3T   = OFF_M2W1S + 24960;        // [128][128]
constexpr size_t OFF_W4T   = OFF_W3T  + 16384;         // [256][256]
constexpr size_t OFF_W5T   = OFF_W4T  + 65536;         // [512][1024]
constexpr size_t OFF_WL1T  = OFF_W5T  + 524288;        // [2048][512]
constexpr size_t OFF_WL2T  = OFF_WL1T + 1048576;       // [512][256]
constexpr size_t OFF_WL3T  = OFF_WL2T + 131072;        // [256][49]

// ---------------- weight prep: dst[c*O+o] = w[o*C+c] * (g?g[o]*inv:1) ----------------
struct TSeg { const float* w; const float* g; float* dst; int O; int C; int start; };
struct TArgs { TSeg seg[10]; int total; };

__global__ __launch_bounds__(256) void prep_transpose(TArgs a) {
  int tid = blockIdx.x * 256 + threadIdx.x;
  if (tid >= a.total) return;
  int s = 0;
  #pragma unroll
  for (int i = 1; i < 10; ++i) if (tid >= a.seg[i].start) s = i;
  const TSeg sg = a.seg[s];
  const int e = tid - sg.start;
  const int c = e / sg.O;
  const int o = e - c * sg.O;
  float v = sg.w[o * sg.C + c];
  if (sg.g) v *= sg.g[o] * BN_INV;
  sg.dst[e] = v;
}

// w1s'[(c*6+i)*64+o] = go[o]*inv * sum_h w1[(o*24+i*4+h)*64+c];  rows 384..389 = gs[o]*inv*ws[o,i]
__global__ __launch_bounds__(256) void prep_w1s(const float* __restrict__ w1, const float* __restrict__ wsm,
                                                const float* __restrict__ go, const float* __restrict__ gs,
                                                float* __restrict__ dst) {
  const int tid = blockIdx.x * 256 + threadIdx.x;
  if (tid >= 390 * 64) return;
  const int ci = tid >> 6, o = tid & 63;
  float v;
  if (ci < 384) {
    const int c = ci / 6, i = ci - c * 6;
    const int base = (o * 24 + i * 4) * 64 + c;
    v = go[o] * BN_INV * (w1[base] + w1[base + 64] + w1[base + 128] + w1[base + 192]);
  } else {
    const int i = ci - 384;
    v = gs[o] * BN_INV * wsm[o * 6 + i];
  }
  dst[tid] = v;
}

// ---------------- KNN: one wave per (b,n), top-16 by iterated argmax ----------------
__global__ __launch_bounds__(256) void knn_kernel(const float* __restrict__ x, int* __restrict__ idxout) {
  const int wid  = (blockIdx.x * blockDim.x + threadIdx.x) >> 6;
  const int lane = threadIdx.x & 63;
  const int b = wid >> 10;
  const int n = wid & (NN - 1);
  const float* xb = x + b * 3 * NN;
  const float x0n = xb[n], x1n = xb[NN + n], x2n = xb[2 * NN + n];
  const float xxn = x0n * x0n + x1n * x1n + x2n * x2n;
  float pd[16];
  #pragma unroll
  for (int j = 0; j < 16; ++j) {
    const int m = j * 64 + lane;
    const float x0 = xb[m], x1 = xb[NN + m], x2 = xb[2 * NN + m];
    const float dot = x0n * x0 + x1n * x1 + x2n * x2;
    const float xxm = x0 * x0 + x1 * x1 + x2 * x2;
    pd[j] = 2.f * dot - xxn - xxm;  // = -||xn-xm||^2, same formula as ref
  }
  for (int r = 0; r < 16; ++r) {
    float bv = pd[0]; int bj = 0;
    #pragma unroll
    for (int j = 1; j < 16; ++j) if (pd[j] > bv) { bv = pd[j]; bj = j; }  // strict > keeps lowest m
    int bm = bj * 64 + lane;
    #pragma unroll
    for (int off = 32; off > 0; off >>= 1) {
      const float ov = __shfl_down(bv, off);
      const int   om = __shfl_down(bm, off);
      if (ov > bv || (ov == bv && om < bm)) { bv = ov; bm = om; }
    }
    bm = __shfl(bm, 0);
    if (lane == 0) idxout[wid * KK + r] = bm;
    const int  cj   = bm >> 6;
    const bool mine = (bm & 63) == lane;
    #pragma unroll
    for (int j = 0; j < 16; ++j) if (mine && j == cj) pd[j] = -INFINITY;
  }
}

// ---------------- shared GEMM inner: 64p x 64o tile, 4x4 per-thread ----------------
template<int CCN>
__device__ __forceinline__ void gemm_chunk(const float* __restrict__ INs, const float* __restrict__ Ws,
                                           int tx4, int ty4, float (&acc)[4][4]) {
  #pragma unroll
  for (int cc = 0; cc < CCN; ++cc) {
    const float4 a = *(const float4*)(INs + cc * 64 + tx4);
    const float4 w = *(const float4*)(Ws  + cc * 64 + ty4);
    acc[0][0] = fmaf(w.x, a.x, acc[0][0]); acc[0][1] = fmaf(w.x, a.y, acc[0][1]);
    acc[0][2] = fmaf(w.x, a.z, acc[0][2]); acc[0][3] = fmaf(w.x, a.w, acc[0][3]);
    acc[1][0] = fmaf(w.y, a.x, acc[1][0]); acc[1][1] = fmaf(w.y, a.y, acc[1][1]);
    acc[1][2] = fmaf(w.y, a.z, acc[1][2]); acc[1][3] = fmaf(w.y, a.w, acc[1][3]);
    acc[2][0] = fmaf(w.z, a.x, acc[2][0]); acc[2][1] = fmaf(w.z, a.y, acc[2][1]);
    acc[2][2] = fmaf(w.z, a.z, acc[2][2]); acc[2][3] = fmaf(w.z, a.w, acc[2][3]);
    acc[3][0] = fmaf(w.w, a.x, acc[3][0]); acc[3][1] = fmaf(w.w, a.y, acc[3][1]);
    acc[3][2] = fmaf(w.w, a.z, acc[3][2]); acc[3][3] = fmaf(w.w, a.w, acc[3][3]);
  }
}

// ---------------- fused mak block: GEMM1 -> GEMM2 -> virtual-Z GEMM3 -> max over k ----------------
// CIN_Y = 6 (m1: y = geo) or 128 (m2: y = graph_feature(x1) gathered from srcp point-major)
template<int CIN_Y>
__global__ __launch_bounds__(256) void mak_kernel(
    const float* __restrict__ x, const int* __restrict__ idxb, const float* __restrict__ srcp,
    const float* __restrict__ w0t, const float* __restrict__ b0v,
    const float* __restrict__ wmt, const float* __restrict__ bmv,
    const float* __restrict__ w1st, const float* __restrict__ bov, const float* __restrict__ bsv,
    float* __restrict__ Xout, float* __restrict__ Xoutp) {
  __shared__ __align__(16) float GEOs[6 * 64];
  __shared__ __align__(16) float Y0s[64 * 64];
  __shared__ __align__(16) float YMs[64 * 64];
  __shared__ __align__(16) float INs[16 * 64];
  __shared__ __align__(16) float Ws[16 * 64];
  __shared__ float red[64 * 17];
  __shared__ int nbrs[64];

  const int t = threadIdx.x;
  const int b = blockIdx.z;
  const int p0 = blockIdx.x * 64;
  const int tx4 = (t & 15) * 4;
  const int ty4 = (t >> 4) * 4;

  if (t < 64) nbrs[t] = idxb[b * NKP + p0 + t];
  __syncthreads();

  // stage geo tile [6][64] from x + idx
  const float* xb = x + b * 3 * NN;
  for (int e = t; e < 384; e += 256) {
    const int i = e >> 6, pp = e & 63;
    const int n = (p0 + pp) >> 4;
    float v;
    if (i < 3) v = xb[i * NN + nbrs[pp]] - xb[i * NN + n];
    else       v = xb[(i - 3) * NN + n];
    GEOs[e] = v;
  }

  float acc[4][4];
  #pragma unroll
  for (int i = 0; i < 4; ++i)
    #pragma unroll
    for (int j = 0; j < 4; ++j) acc[i][j] = 0.f;

  // ---- GEMM1: y -> 64 ----
  if constexpr (CIN_Y == 6) {
    for (int e = t; e < 384; e += 256) Ws[e] = w0t[e];
    __syncthreads();
    gemm_chunk<6>(GEOs, Ws, tx4, ty4, acc);
    __syncthreads();
  } else {
    constexpr int CH = CIN_Y / 2;
    for (int c0 = 0; c0 < CIN_Y; c0 += 16) {
      const int pp = t & 63, cq = t >> 6;
      const int c = c0 + cq * 4;
      const int n = (p0 + pp) >> 4;
      float4 v;
      if (c < CH) {
        const float4 vn = *(const float4*)(srcp + (size_t)(b * NN + nbrs[pp]) * CH + c);
        const float4 vc = *(const float4*)(srcp + (size_t)(b * NN + n) * CH + c);
        v.x = vn.x - vc.x; v.y = vn.y - vc.y; v.z = vn.z - vc.z; v.w = vn.w - vc.w;
      } else {
        v = *(const float4*)(srcp + (size_t)(b * NN + n) * CH + (c - CH));
      }
      INs[(cq * 4 + 0) * 64 + pp] = v.x;
      INs[(cq * 4 + 1) * 64 + pp] = v.y;
      INs[(cq * 4 + 2) * 64 + pp] = v.z;
      INs[(cq * 4 + 3) * 64 + pp] = v.w;
      for (int e = t; e < 1024; e += 256) Ws[e] = w0t[c0 * 64 + e];
      __syncthreads();
      gemm_chunk<16>(INs, Ws, tx4, ty4, acc);
      __syncthreads();
    }
  }
  #pragma unroll
  for (int i = 0; i < 4; ++i) {
    const float bb = b0v[ty4 + i];
    #pragma unroll
    for (int j = 0; j < 4; ++j) Y0s[(ty4 + i) * 64 + tx4 + j] = lrelu(acc[i][j] + bb);
  }
  __syncthreads();

  // ---- GEMM2: 64 -> 64 ----
  #pragma unroll
  for (int i = 0; i < 4; ++i)
    #pragma unroll
    for (int j = 0; j < 4; ++j) acc[i][j] = 0.f;
  for (int c0 = 0; c0 < 64; c0 += 16) {
    for (int e = t; e < 1024; e += 256) Ws[e] = wmt[c0 * 64 + e];
    __syncthreads();
    gemm_chunk<16>(Y0s + c0 * 64, Ws, tx4, ty4, acc);
    __syncthreads();
  }
  #pragma unroll
  for (int i = 0; i < 4; ++i) {
    const float bb = bmv[ty4 + i];
    #pragma unroll
    for (int j = 0; j < 4; ++j) YMs[(ty4 + i) * 64 + tx4 + j] = lrelu(acc[i][j] + bb);
  }
  __syncthreads();

  // ---- GEMM3: virtual Z (384 = ym x geo outer product channels) + 6 idt channels ----
  #pragma unroll
  for (int i = 0; i < 4; ++i)
    #pragma unroll
    for (int j = 0; j < 4; ++j) acc[i][j] = 0.f;
  for (int c0 = 0; c0 < 384; c0 += 16) {
    for (int e = t; e < 1024; e += 256) {
      const int cl = e >> 6, pp = e & 63;
      const int ci = c0 + cl;
      const int ch = ci / 6, ii = ci - ch * 6;
      INs[e] = YMs[ch * 64 + pp] * GEOs[ii * 64 + pp];
    }
    for (int e = t; e < 1024; e += 256) Ws[e] = w1st[c0 * 64 + e];
    __syncthreads();
    gemm_chunk<16>(INs, Ws, tx4, ty4, acc);
    __syncthreads();
  }
  for (int e = t; e < 384; e += 256) Ws[e] = w1st[384 * 64 + e];
  __syncthreads();
  gemm_chunk<6>(GEOs, Ws, tx4, ty4, acc);  // idt path: channels = geo directly
  __syncthreads();

  // ---- epilogue: lrelu(out + bo + bs), max over k=16 ----
  const int tx = t & 15;
  #pragma unroll
  for (int i = 0; i < 4; ++i) {
    const int o = ty4 + i;
    const float bb = bov[o] + bsv[o];
    float m = lrelu(acc[i][0] + bb);
    m = fmaxf(m, lrelu(acc[i][1] + bb));
    m = fmaxf(m, lrelu(acc[i][2] + bb));
    m = fmaxf(m, lrelu(acc[i][3] + bb));
    red[o * 17 + tx] = m;  // thread's 4 points share one n (tx/4)
  }
  __syncthreads();
  {
    const int o = t & 63, nl = t >> 6;
    const float m = fmaxf(fmaxf(red[o * 17 + nl * 4 + 0], red[o * 17 + nl * 4 + 1]),
                          fmaxf(red[o * 17 + nl * 4 + 2], red[o * 17 + nl * 4 + 3]));
    const int n = blockIdx.x * 4 + nl;
    Xout[(b * 64 + o) * NN + n] = m;
    Xoutp[(b * NN + n) * 64 + o] = m;
  }
}

// ---------------- edge conv: gather graph feature, GEMM, lrelu, max over k ----------------
template<int CIN, int COUT>
__global__ __launch_bounds__(256) void conv_maxk(const float* __restrict__ srcp, const int* __restrict__ idxb,
                                                 const float* __restrict__ wt, const float* __restrict__ bias,
                                                 float* __restrict__ Xout, float* __restrict__ Xoutp) {
  __shared__ __align__(16) float INs[16 * 64];
  __shared__ __align__(16) float Ws[16 * 64];
  __shared__ float red[64 * 17];
  __shared__ int nbrs[64];
  constexpr int CH = CIN / 2;

  const int t = threadIdx.x;
  const int b = blockIdx.z;
  const int p0 = blockIdx.x * 64;
  const int og0 = blockIdx.y * 64;
  const int tx4 = (t & 15) * 4;
  const int ty4 = (t >> 4) * 4;

  if (t < 64) nbrs[t] = idxb[b * NKP + p0 + t];
  __syncthreads();

  float acc[4][4];
  #pragma unroll
  for (int i = 0; i < 4; ++i)
    #pragma unroll
    for (int j = 0; j < 4; ++j) acc[i][j] = 0.f;

  for (int c0 = 0; c0 < CIN; c0 += 16) {
    const int pp = t & 63, cq = t >> 6;
    const int c = c0 + cq * 4;
    const int n = (p0 + pp) >> 4;
    float4 v;
    if (c < CH) {
      const float4 vn = *(const float4*)(srcp + (size_t)(b * NN + nbrs[pp]) * CH + c);
      const float4 vc = *(const float4*)(srcp + (size_t)(b * NN + n) * CH + c);
      v.x = vn.x - vc.x; v.y = vn.y - vc.y; v.z = vn.z - vc.z; v.w = vn.w - vc.w;
    } else {
      v = *(const float4*)(srcp + (size_t)(b * NN + n) * CH + (c - CH));
    }
    INs[(cq * 4 + 0) * 64 + pp] = v.x;
    INs[(cq * 4 + 1) * 64 + pp] = v.y;
    INs[(cq * 4 + 2) * 64 + pp] = v.z;
    INs[(cq * 4 + 3) * 64 + pp] = v.w;
    for (int e = t; e < 1024; e += 256) Ws[e] = wt[(c0 + (e >> 6)) * COUT + og0 + (e & 63)];
    __syncthreads();
    gemm_chunk<16>(INs, Ws, tx4, ty4, acc);
    __syncthreads();
  }

  const int tx = t & 15;
  #pragma unroll
  for (int i = 0; i < 4; ++i) {
    const int o = ty4 + i;
    const float bb = bias[og0 + o];
    float m = lrelu(acc[i][0] + bb);
    m = fmaxf(m, lrelu(acc[i][1] + bb));
    m = fmaxf(m, lrelu(acc[i][2] + bb));
    m = fmaxf(m, lrelu(acc[i][3] + bb));
    red[o * 17 + tx] = m;
  }
  __syncthreads();
  {
    const int o = t & 63, nl = t >> 6;
    const float m = fmaxf(fmaxf(red[o * 17 + nl * 4 + 0], red[o * 17 + nl * 4 + 1]),
                          fmaxf(red[o * 17 + nl * 4 + 2], red[o * 17 + nl * 4 + 3]));
    const int n = blockIdx.x * 4 + nl;
    Xout[(b * COUT + og0 + o) * NN + n] = m;
    if (Xoutp) Xoutp[(b * NN + n) * COUT + og0 + o] = m;
  }
}

// ---------------- conv5: concat(x1..x4) -> 1024ch, lrelu, partial max/sum over n ----------------
__global__ __launch_bounds__(256) void conv5_kernel(const float* __restrict__ X1, const float* __restrict__ X2,
                                                    const float* __restrict__ X3, const float* __restrict__ X4,
                                                    const float* __restrict__ w5t, const float* __restrict__ b5,
                                                    float* __restrict__ PMAX, float* __restrict__ PSUM) {
  __shared__ __align__(16) float INs[16 * 64];
  __shared__ __align__(16) float Ws[16 * 64];
  __shared__ float redm[64 * 17];
  __shared__ float reds[64 * 17];

  const int t = threadIdx.x;
  const int b = blockIdx.z;
  const int n0 = blockIdx.x * 64;
  const int og0 = blockIdx.y * 64;
  const int tx4 = (t & 15) * 4;
  const int ty4 = (t >> 4) * 4;

  float acc[4][4];
  #pragma unroll
  for (int i = 0; i < 4; ++i)
    #pragma unroll
    for (int j = 0; j < 4; ++j) acc[i][j] = 0.f;

  for (int c0 = 0; c0 < 512; c0 += 16) {
    for (int e = t; e < 1024; e += 256) {
      const int cl = e >> 6, pp = e & 63;
      const int c = c0 + cl;
      const float* src;
      if (c < 64)       src = X1 + (size_t)(b * 64 + c) * NN;
      else if (c < 128) src = X2 + (size_t)(b * 64 + (c - 64)) * NN;
      else if (c < 256) src = X3 + (size_t)(b * 128 + (c - 128)) * NN;
      else              src = X4 + (size_t)(b * 256 + (c - 256)) * NN;
      INs[e] = src[n0 + pp];
    }
    for (int e = t; e < 1024; e += 256) Ws[e] = w5t[(c0 + (e >> 6)) * 1024 + og0 + (e & 63)];
    __syncthreads();
    gemm_chunk<16>(INs, Ws, tx4, ty4, acc);
    __syncthreads();
  }

  const int tx = t & 15;
  #pragma unroll
  for (int i = 0; i < 4; ++i) {
    const int o = ty4 + i;
    const float bb = b5[og0 + o];
    const float v0 = lrelu(acc[i][0] + bb), v1 = lrelu(acc[i][1] + bb);
    const float v2 = lrelu(acc[i][2] + bb), v3 = lrelu(acc[i][3] + bb);
    redm[o * 17 + tx] = fmaxf(fmaxf(v0, v1), fmaxf(v2, v3));
    reds[o * 17 + tx] = v0 + v1 + v2 + v3;
  }
  __syncthreads();
  if (t < 64) {
    float m = -INFINITY, s = 0.f;
    for (int q = 0; q < 16; ++q) { m = fmaxf(m, redm[t * 17 + q]); s += reds[t * 17 + q]; }
    PMAX[(size_t)(b * 16 + blockIdx.x) * 1024 + og0 + t] = m;
    PSUM[(size_t)(b * 16 + blockIdx.x) * 1024 + og0 + t] = s;
  }
}

__global__ __launch_bounds__(256) void reduce5(const float* __restrict__ PMAX, const float* __restrict__ PSUM,
                                               float* __restrict__ XPg) {
  const int tid = blockIdx.x * 256 + threadIdx.x;  // 8192
  const int b = tid >> 10, o = tid & 1023;
  float m = -INFINITY, s = 0.f;
  for (int pt = 0; pt < 16; ++pt) {
    m = fmaxf(m, PMAX[(size_t)(b * 16 + pt) * 1024 + o]);
    s += PSUM[(size_t)(b * 16 + pt) * 1024 + o];
  }
  XPg[b * 2048 + o] = m;
  XPg[b * 2048 + 1024 + o] = s * (1.f / 1024.f);
}

// ---------------- FC head ----------------
__global__ __launch_bounds__(256) void fc1_kernel(const float* __restrict__ XPg, const float* __restrict__ wl1t,
                                                  const float* __restrict__ bn4_b, float* __restrict__ XF1) {
  __shared__ float red[64 * 5];
  const int t = threadIdx.x;
  const int b = blockIdx.y;
  const int o = blockIdx.x * 64 + (t & 63);
  const int cq = t >> 6;
  const float* xp = XPg + b * 2048;
  float acc = 0.f;
  for (int c = cq * 512; c < cq * 512 + 512; ++c) acc = fmaf(wl1t[c * 512 + o], xp[c], acc);
  red[(t & 63) * 5 + cq] = acc;
  __syncthreads();
  if (t < 64) {
    const int oo = blockIdx.x * 64 + t;
    const float v = red[t * 5] + red[t * 5 + 1] + red[t * 5 + 2] + red[t * 5 + 3] + bn4_b[oo];
    XF1[b * 512 + oo] = lrelu(v);
  }
}

__global__ __launch_bounds__(256) void fc2_kernel(const float* __restrict__ XF1, const float* __restrict__ wl2t,
                                                  const float* __restrict__ bl2, const float* __restrict__ bn5_g,
                                                  const float* __restrict__ bn5_b, float* __restrict__ XF2) {
  __shared__ float red[64 * 5];
  const int t = threadIdx.x;
  const int b = blockIdx.y;
  const int o = blockIdx.x * 64 + (t & 63);
  const int cq = t >> 6;
  const float* xf = XF1 + b * 512;
  float acc = 0.f;
  for (int c = cq * 128; c < cq * 128 + 128; ++c) acc = fmaf(wl2t[c * 256 + o], xf[c], acc);
  red[(t & 63) * 5 + cq] = acc;
  __syncthreads();
  if (t < 64) {
    const int oo = blockIdx.x * 64 + t;
    const float bias = bl2[oo] * (bn5_g[oo] * BN_INV) + bn5_b[oo];
    const float v = red[t * 5] + red[t * 5 + 1] + red[t * 5 + 2] + red[t * 5 + 3] + bias;
    XF2[b * 256 + oo] = lrelu(v);
  }
}

__global__ __launch_bounds__(256) void fc3_kernel(const float* __restrict__ XF2, const float* __restrict__ wl3t,
                                                  const float* __restrict__ bl3, float* __restrict__ out) {
  __shared__ float red[64 * 5];
  const int t = threadIdx.x;
  const int b = blockIdx.y;
  const int ol = t & 63;
  const int cq = t >> 6;
  const float* xf = XF2 + b * 256;
  float acc = 0.f;
  if (ol < 49) for (int c = cq * 64; c < cq * 64 + 64; ++c) acc = fmaf(wl3t[c * 49 + ol], xf[c], acc);
  red[ol * 5 + cq] = acc;
  __syncthreads();
  if (t < 49) out[b * 49 + t] = red[t * 5] + red[t * 5 + 1] + red[t * 5 + 2] + red[t * 5 + 3] + bl3[t];
}

// ---------------- host ----------------
extern "C" void kernel_launch(void* const* d_in, const int* in_sizes, int n_in,
                              void* d_out, int out_size, void* d_ws, size_t ws_size,
                              hipStream_t stream) {
  (void)in_sizes; (void)n_in; (void)out_size; (void)ws_size;
  const float* x     = (const float*)d_in[0];
  const float* m1_w0 = (const float*)d_in[1];
  const float* m1_g0 = (const float*)d_in[2];
  const float* m1_b0 = (const float*)d_in[3];
  const float* m1_wm = (const float*)d_in[4];
  const float* m1_gm = (const float*)d_in[5];
  const float* m1_bm = (const float*)d_in[6];
  const float* m1_w1 = (const float*)d_in[7];
  const float* m1_go = (const float*)d_in[8];
  const float* m1_bo = (const float*)d_in[9];
  const float* m1_ws = (const float*)d_in[10];
  const float* m1_gs = (const float*)d_in[11];
  const float* m1_bs = (const float*)d_in[12];
  const float* m2_w0 = (const float*)d_in[13];
  const float* m2_g0 = (const float*)d_in[14];
  const float* m2_b0 = (const float*)d_in[15];
  const float* m2_wm = (const float*)d_in[16];
  const float* m2_gm = (const float*)d_in[17];
  const float* m2_bm = (const float*)d_in[18];
  const float* m2_w1 = (const float*)d_in[19];
  const float* m2_go = (const float*)d_in[20];
  const float* m2_bo = (const float*)d_in[21];
  const float* m2_ws = (const float*)d_in[22];
  const float* m2_gs = (const float*)d_in[23];
  const float* m2_bs = (const float*)d_in[24];
  const float* w3    = (const float*)d_in[25];
  const float* g3    = (const float*)d_in[26];
  const float* b3    = (const float*)d_in[27];
  const float* w4    = (const float*)d_in[28];
  const float* g4    = (const float*)d_in[29];
  const float* b4    = (const float*)d_in[30];
  const float* w5    = (const float*)d_in[31];
  const float* g5    = (const float*)d_in[32];
  const float* b5    = (const float*)d_in[33];
  const float* wl1   = (const float*)d_in[34];
  const float* bn4_g = (const float*)d_in[35];
  const float* bn4_b = (const float*)d_in[36];
  const float* wl2   = (const float*)d_in[37];
  const float* bl2   = (const float*)d_in[38];
  const float* bn5_g = (const float*)d_in[39];
  const float* bn5_b = (const float*)d_in[40];
  const float* wl3   = (const float*)d_in[41];
  const float* bl3   = (const float*)d_in[42];

  float* wsf = (float*)d_ws;
  int*   IDX  = (int*)d_ws;
  float* X1   = wsf + OFF_X1;
  float* X1P  = wsf + OFF_X1P;
  float* X2   = wsf + OFF_X2;
  float* X2P  = wsf + OFF_X2P;
  float* X3   = wsf + OFF_X3;
  float* X3P  = wsf + OFF_X3P;
  float* X4   = wsf + OFF_X4;
  float* PMAX = wsf + OFF_PMAX;
  float* PSUM = wsf + OFF_PSUM;
  float* XPg  = wsf + OFF_XP;
  float* XF1  = wsf + OFF_XF1;
  float* XF2  = wsf + OFF_XF2;
  float* M1W0T = wsf + OFF_M1W0T;
  float* M1WMT = wsf + OFF_M1WMT;
  float* M1W1S = wsf + OFF_M1W1S;
  float* M2W0T = wsf + OFF_M2W0T;
  float* M2WMT = wsf + OFF_M2WMT;
  float* M2W1S = wsf + OFF_M2W1S;
  float* W3T  = wsf + OFF_W3T;
  float* W4T  = wsf + OFF_W4T;
  float* W5T  = wsf + OFF_W5T;
  float* WL1T = wsf + OFF_WL1T;
  float* WL2T = wsf + OFF_WL2T;
  float* WL3T = wsf + OFF_WL3T;

  // weight prep (inputs are re-poisoned every call, so re-derive every launch)
  TArgs ta;
  int st = 0;
  auto set = [&](int s, const float* w, const float* g, float* dst, int O, int C) {
    ta.seg[s].w = w; ta.seg[s].g = g; ta.seg[s].dst = dst; ta.seg[s].O = O; ta.seg[s].C = C; ta.seg[s].start = st;
    st += O * C;
  };
  set(0, m1_w0, m1_g0, M1W0T, 64, 6);
  set(1, m1_wm, m1_gm, M1WMT, 64, 64);
  set(2, m2_w0, m2_g0, M2W0T, 64, 128);
  set(3, m2_wm, m2_gm, M2WMT, 64, 64);
  set(4, w3,    g3,    W3T,  128, 128);
  set(5, w4,    g4,    W4T,  256, 256);
  set(6, w5,    g5,    W5T, 1024, 512);
  set(7, wl1,   bn4_g, WL1T, 512, 2048);
  set(8, wl2,   bn5_g, WL2T, 256, 512);
  set(9, wl3,   nullptr, WL3T, 49, 256);
  ta.total = st;  // 1815168

  hipLaunchKernelGGL(prep_transpose, dim3((ta.total + 255) / 256), dim3(256), 0, stream, ta);
  hipLaunchKernelGGL(prep_w1s, dim3(98), dim3(256), 0, stream, m1_w1, m1_ws, m1_go, m1_gs, M1W1S);
  hipLaunchKernelGGL(prep_w1s, dim3(98), dim3(256), 0, stream, m2_w1, m2_ws, m2_go, m2_gs, M2W1S);

  hipLaunchKernelGGL(knn_kernel, dim3(2048), dim3(256), 0, stream, x, IDX);

  hipLaunchKernelGGL((mak_kernel<6>),   dim3(256, 1, BB), dim3(256), 0, stream,
                     x, IDX, (const float*)nullptr, M1W0T, m1_b0, M1WMT, m1_bm, M1W1S, m1_bo, m1_bs, X1, X1P);
  hipLaunchKernelGGL((mak_kernel<128>), dim3(256, 1, BB), dim3(256), 0, stream,
                     x, IDX, X1P, M2W0T, m2_b0, M2WMT, m2_bm, M2W1S, m2_bo, m2_bs, X2, X2P);

  hipLaunchKernelGGL((conv_maxk<128, 128>), dim3(256, 2, BB), dim3(256), 0, stream,
                     X2P, IDX, W3T, b3, X3, X3P);
  hipLaunchKernelGGL((conv_maxk<256, 256>), dim3(256, 4, BB), dim3(256), 0, stream,
                     X3P, IDX, W4T, b4, X4, (float*)nullptr);

  hipLaunchKernelGGL(conv5_kernel, dim3(16, 16, BB), dim3(256), 0, stream,
                     X1, X2, X3, X4, W5T, b5, PMAX, PSUM);
  hipLaunchKernelGGL(reduce5, dim3(32), dim3(256), 0, stream, PMAX, PSUM, XPg);

  hipLaunchKernelGGL(fc1_kernel, dim3(8, BB), dim3(256), 0, stream, XPg, WL1T, bn4_b, XF1);
  hipLaunchKernelGGL(fc2_kernel, dim3(4, BB), dim3(256), 0, stream, XF1, WL2T, bl2, bn5_g, bn5_b, XF2);
  hipLaunchKernelGGL(fc3_kernel, dim3(1, BB), dim3(256), 0, stream, XF2, WL3T, bl3, (float*)d_out);
}

// Round 2
// 618.300 us; speedup vs baseline: 1.7313x; 1.7313x over previous
//
#include <hip/hip_runtime.h>
#include <math.h>

#define BB 8
#define NN 1024
#define KK 16
#define NKP (NN*KK)
#define BN_INV 0.99999500003749981f

typedef unsigned short u16;
typedef __attribute__((ext_vector_type(8))) short short8;
typedef __attribute__((ext_vector_type(4))) float f32x4;

#define MFMA16(a,b,c) __builtin_amdgcn_mfma_f32_16x16x32_bf16(a,b,c,0,0,0)

__device__ __forceinline__ float lrelu(float v) { return v >= 0.f ? v : 0.2f * v; }

__device__ __forceinline__ u16 f2bf(float f) {
  union { float f; unsigned u; } v; v.f = f;
  unsigned r = v.u + 0x7fff + ((v.u >> 16) & 1);
  return (u16)(r >> 16);
}
__device__ __forceinline__ float bf2f(u16 s) {
  union { unsigned u; float f; } v; v.u = ((unsigned)s) << 16;
  return v.f;
}

// ---------------- workspace byte offsets ----------------
constexpr size_t OFF_IDX   = 0;          // int[8*1024*16]
constexpr size_t OFF_X1P   = 524288;     // bf16 [8][1024][64]
constexpr size_t OFF_X2P   = 1572864;
constexpr size_t OFF_X3P   = 2621440;    // bf16 [8][1024][128]
constexpr size_t OFF_X4P   = 4718592;    // bf16 [8][1024][256]
constexpr size_t OFF_PMAX  = 8912896;    // f32 [8][16][1024]
constexpr size_t OFF_PSUM  = 9437184;
constexpr size_t OFF_XP    = 9961472;    // f32 [8][2048]
constexpr size_t OFF_XF1   = 10027008;   // f32 [8][512]
constexpr size_t OFF_XF2   = 10043392;   // f32 [8][256]
constexpr size_t OFF_M1W0  = 10051584;   // bf16 [64][32] (6 real, pad 0)
constexpr size_t OFF_M1WM  = 10055680;   // bf16 [64][64]
constexpr size_t OFF_M1W1S = 10063872;   // bf16 [64][416]
constexpr size_t OFF_M2W0  = 10117120;   // bf16 [64][128]
constexpr size_t OFF_M2WM  = 10133504;   // bf16 [64][64]
constexpr size_t OFF_M2W1S = 10141696;   // bf16 [64][416]
constexpr size_t OFF_W3    = 10194944;   // bf16 [128][128]
constexpr size_t OFF_W4    = 10227712;   // bf16 [256][256]
constexpr size_t OFF_W5    = 10358784;   // bf16 [1024][512]
constexpr size_t OFF_WL1T  = 11407360;   // f32 [2048][512]
constexpr size_t OFF_WL2T  = 15601664;   // f32 [512][256]
constexpr size_t OFF_WL3T  = 16125952;   // f32 [256][49]

// ---------------- weight prep: bf16 [o][Cp] with BN gamma fold ----------------
struct SSeg { const float* w; const float* g; u16* dst; int C; int cpl2; int start; };
struct SArgs { SSeg seg[7]; int total; };

__global__ __launch_bounds__(256) void prep_scale_bf16(SArgs a) {
  const int tid = blockIdx.x * 256 + threadIdx.x;
  if (tid >= a.total) return;
  int s = 0;
  #pragma unroll
  for (int i = 1; i < 7; ++i) if (tid >= a.seg[i].start) s = i;
  const SSeg sg = a.seg[s];
  const int e = tid - sg.start;
  const int o = e >> sg.cpl2;
  const int c = e & ((1 << sg.cpl2) - 1);
  float v = 0.f;
  if (c < sg.C) v = sg.w[o * sg.C + c] * sg.g[o] * BN_INV;
  sg.dst[e] = f2bf(v);
}

// w1s[o][ci]: ci<384: ci=ii*64+ch -> go*inv*sum_h w1[(o*24+ii*4+h)*64+ch];
// 384..389: gs*inv*ws[o*6+ii]; 390..415: 0.   layout [64][416] bf16
__global__ __launch_bounds__(256) void prep_w1s_bf16(const float* __restrict__ w1, const float* __restrict__ wsm,
                                                     const float* __restrict__ go, const float* __restrict__ gs,
                                                     u16* __restrict__ dst) {
  const int tid = blockIdx.x * 256 + threadIdx.x;
  if (tid >= 64 * 416) return;
  const int o = tid / 416, ci = tid - o * 416;
  float v = 0.f;
  if (ci < 384) {
    const int ii = ci >> 6, ch = ci & 63;
    const int base = (o * 24 + ii * 4) * 64 + ch;
    v = go[o] * BN_INV * (w1[base] + w1[base + 64] + w1[base + 128] + w1[base + 192]);
  } else if (ci < 390) {
    v = gs[o] * BN_INV * wsm[o * 6 + (ci - 384)];
  }
  dst[tid] = f2bf(v);
}

// FC weights: f32 transposed [c][o] with gamma fold
struct TSeg { const float* w; const float* g; float* dst; int O; int C; int start; };
struct TArgs3 { TSeg seg[3]; int total; };

__global__ __launch_bounds__(256) void prep_transpose_f32(TArgs3 a) {
  const int tid = blockIdx.x * 256 + threadIdx.x;
  if (tid >= a.total) return;
  int s = 0;
  #pragma unroll
  for (int i = 1; i < 3; ++i) if (tid >= a.seg[i].start) s = i;
  const TSeg sg = a.seg[s];
  const int e = tid - sg.start;
  const int c = e / sg.O;
  const int o = e - c * sg.O;
  float v = sg.w[o * sg.C + c];
  if (sg.g) v *= sg.g[o] * BN_INV;
  sg.dst[e] = v;
}

// ---------------- KNN (exact fp32, unchanged) ----------------
__global__ __launch_bounds__(256) void knn_kernel(const float* __restrict__ x, int* __restrict__ idxout) {
  const int wid  = (blockIdx.x * blockDim.x + threadIdx.x) >> 6;
  const int lane = threadIdx.x & 63;
  const int b = wid >> 10;
  const int n = wid & (NN - 1);
  const float* xb = x + b * 3 * NN;
  const float x0n = xb[n], x1n = xb[NN + n], x2n = xb[2 * NN + n];
  const float xxn = x0n * x0n + x1n * x1n + x2n * x2n;
  float pd[16];
  #pragma unroll
  for (int j = 0; j < 16; ++j) {
    const int m = j * 64 + lane;
    const float x0 = xb[m], x1 = xb[NN + m], x2 = xb[2 * NN + m];
    const float dot = x0n * x0 + x1n * x1 + x2n * x2;
    const float xxm = x0 * x0 + x1 * x1 + x2 * x2;
    pd[j] = 2.f * dot - xxn - xxm;
  }
  for (int r = 0; r < 16; ++r) {
    float bv = pd[0]; int bj = 0;
    #pragma unroll
    for (int j = 1; j < 16; ++j) if (pd[j] > bv) { bv = pd[j]; bj = j; }
    int bm = bj * 64 + lane;
    #pragma unroll
    for (int off = 32; off > 0; off >>= 1) {
      const float ov = __shfl_down(bv, off);
      const int   om = __shfl_down(bm, off);
      if (ov > bv || (ov == bv && om < bm)) { bv = ov; bm = om; }
    }
    bm = __shfl(bm, 0);
    if (lane == 0) idxout[wid * KK + r] = bm;
    const int  cj   = bm >> 6;
    const bool mine = (bm & 63) == lane;
    #pragma unroll
    for (int j = 0; j < 16; ++j) if (mine && j == cj) pd[j] = -INFINITY;
  }
}

// ---------------- MFMA helpers ----------------
// swizzled [64p][32c] bf16 tile: group g (8 c's) of row p stored at pos = g ^ (p&3) ^ ((p>>2)&3)
__device__ __forceinline__ short8 bfrag32(const u16* INs, int pl, int quad) {
  const int pos = quad ^ (pl & 3) ^ ((pl >> 2) & 3);
  return *(const short8*)(INs + pl * 32 + pos * 8);
}
// swizzled [64p][64c] tile: group g of row p at pos = g ^ (p&7)
__device__ __forceinline__ short8 bfrag64(const u16* T, int pl, int quad, int c0) {
  const int pos = ((c0 >> 3) + quad) ^ (pl & 7);
  return *(const short8*)(T + pl * 64 + pos * 8);
}

__device__ __forceinline__ uint4 diff8(const u16* a, const u16* b) {
  union { uint4 q; u16 s[8]; } ua, ub, r;
  ua.q = *(const uint4*)a; ub.q = *(const uint4*)b;
  #pragma unroll
  for (int j = 0; j < 8; ++j) r.s[j] = f2bf(bf2f(ua.s[j]) - bf2f(ub.s[j]));
  return r.q;
}

// stage 32 channels [c0,c0+32) of gathered graph-feature into swizzled [64][32]
template<int CH>
__device__ __forceinline__ void stage_gf(u16* INs, const u16* __restrict__ srcp,
                                         const int* nbrs, int b, int p0, int c0, int t) {
  const int p = t & 63, cq = t >> 6;
  const int c = c0 + cq * 8;
  const int n = (p0 + p) >> 4;
  uint4 val;
  if (c < CH) {
    val = diff8(srcp + ((size_t)(b * NN + nbrs[p]) * CH + c),
                srcp + ((size_t)(b * NN + n) * CH + c));
  } else {
    val = *(const uint4*)(srcp + ((size_t)(b * NN + n) * CH + (c - CH)));
  }
  const int pos = cq ^ (p & 3) ^ ((p >> 2) & 3);
  *(uint4*)(INs + p * 32 + pos * 8) = val;
}

// write one D-frag (4 o's) as bf16 with bias+lrelu into swizzled [64][64] tile
__device__ __forceinline__ void writeD64(u16* T, int pl, int quad, const f32x4 a,
                                         const float* __restrict__ bias, int obase) {
  union { ushort4 v; u16 s[4]; } pk;
  #pragma unroll
  for (int r = 0; r < 4; ++r) pk.s[r] = f2bf(lrelu(a[r] + bias[obase + quad * 4 + r]));
  const int g = (obase + quad * 4) >> 3;
  const int pos = g ^ (pl & 7);
  *(ushort4*)(T + pl * 64 + pos * 8 + (quad & 1) * 4) = pk.v;
}

// ---------------- fused mak block (MFMA) ----------------
template<int CIN_Y>
__global__ __launch_bounds__(256) void mak_mfma(
    const float* __restrict__ x, const int* __restrict__ idxb, const u16* __restrict__ srcp,
    const u16* __restrict__ w0b, const float* __restrict__ b0v,
    const u16* __restrict__ wmb, const float* __restrict__ bmv,
    const u16* __restrict__ w1s, const float* __restrict__ bov, const float* __restrict__ bsv,
    u16* __restrict__ Xoutp) {
  __shared__ __align__(16) u16 GEOs[64 * 32];
  __shared__ __align__(16) u16 Y0s[64 * 64];
  __shared__ __align__(16) u16 YMs[64 * 64];
  __shared__ __align__(16) u16 INs[64 * 32];
  __shared__ int nbrs[64];

  const int t = threadIdx.x;
  const int b = blockIdx.z;
  const int p0 = blockIdx.x * 64;
  const int w = t >> 6, l = t & 63;
  const int quad = l >> 4, l15 = l & 15;
  const int pl = w * 16 + l15;

  if (t < 64) nbrs[t] = idxb[b * NKP + p0 + t];
  __syncthreads();

  // stage geo [64p][32c] (6 real channels: 0..2 diff, 3..5 ctr, rest 0)
  const float* xb = x + b * 3 * NN;
  {
    const int p = t & 63, cq = t >> 6;
    const int n = (p0 + p) >> 4;
    union { uint4 q; u16 s[8]; } val;
    #pragma unroll
    for (int j = 0; j < 8; ++j) {
      const int c = cq * 8 + j;
      float v = 0.f;
      if (c < 3)      v = xb[c * NN + nbrs[p]] - xb[c * NN + n];
      else if (c < 6) v = xb[(c - 3) * NN + n];
      val.s[j] = f2bf(v);
    }
    const int pos = cq ^ (p & 3) ^ ((p >> 2) & 3);
    *(uint4*)(GEOs + p * 32 + pos * 8) = val.q;
  }
  __syncthreads();

  f32x4 acc[4];
  #pragma unroll
  for (int i = 0; i < 4; ++i) acc[i] = (f32x4)0.f;

  // ---- GEMM1: y -> 64 ----
  if constexpr (CIN_Y == 6) {
    const short8 bf = bfrag32(GEOs, pl, quad);
    #pragma unroll
    for (int at = 0; at < 4; ++at) {
      const short8 af = *(const short8*)(w0b + (size_t)(at * 16 + l15) * 32 + quad * 8);
      acc[at] = MFMA16(af, bf, acc[at]);
    }
  } else {
    for (int c0 = 0; c0 < CIN_Y; c0 += 32) {
      stage_gf<64>(INs, srcp, nbrs, b, p0, c0, t);
      __syncthreads();
      const short8 bf = bfrag32(INs, pl, quad);
      #pragma unroll
      for (int at = 0; at < 4; ++at) {
        const short8 af = *(const short8*)(w0b + (size_t)(at * 16 + l15) * CIN_Y + c0 + quad * 8);
        acc[at] = MFMA16(af, bf, acc[at]);
      }
      __syncthreads();
    }
  }
  #pragma unroll
  for (int at = 0; at < 4; ++at) writeD64(Y0s, pl, quad, acc[at], b0v, at * 16);
  __syncthreads();

  // ---- GEMM2: 64 -> 64 ----
  #pragma unroll
  for (int i = 0; i < 4; ++i) acc[i] = (f32x4)0.f;
  #pragma unroll
  for (int c0 = 0; c0 < 64; c0 += 32) {
    const short8 bf = bfrag64(Y0s, pl, quad, c0);
    #pragma unroll
    for (int at = 0; at < 4; ++at) {
      const short8 af = *(const short8*)(wmb + (size_t)(at * 16 + l15) * 64 + c0 + quad * 8);
      acc[at] = MFMA16(af, bf, acc[at]);
    }
  }
  #pragma unroll
  for (int at = 0; at < 4; ++at) writeD64(YMs, pl, quad, acc[at], bmv, at * 16);
  __syncthreads();

  // ---- GEMM3: 384 virtual channels (ii-major: ci = ii*64 + ch) + idt ----
  #pragma unroll
  for (int i = 0; i < 4; ++i) acc[i] = (f32x4)0.f;
  for (int k = 0; k < 12; ++k) {
    const int ii = k >> 1, ch0 = (k & 1) * 32;
    {
      const int p = t & 63, cq = t >> 6;
      const int ch = ch0 + cq * 8;
      const int gy = (ch >> 3) ^ (p & 7);
      union { uint4 q; u16 s[8]; } ym, r;
      ym.q = *(const uint4*)(YMs + p * 64 + gy * 8);
      const int posg = (p & 3) ^ ((p >> 2) & 3);
      const float ge = bf2f(GEOs[p * 32 + posg * 8 + ii]);
      #pragma unroll
      for (int j = 0; j < 8; ++j) r.s[j] = f2bf(bf2f(ym.s[j]) * ge);
      const int pos = cq ^ (p & 3) ^ ((p >> 2) & 3);
      *(uint4*)(INs + p * 32 + pos * 8) = r.q;
    }
    __syncthreads();
    const short8 bf = bfrag32(INs, pl, quad);
    #pragma unroll
    for (int at = 0; at < 4; ++at) {
      const short8 af = *(const short8*)(w1s + (size_t)(at * 16 + l15) * 416 + k * 32 + quad * 8);
      acc[at] = MFMA16(af, bf, acc[at]);
    }
    __syncthreads();
  }
  {  // idt chunk: B = geo tile, A cols 384..415 (390+ are zero)
    const short8 bf = bfrag32(GEOs, pl, quad);
    #pragma unroll
    for (int at = 0; at < 4; ++at) {
      const short8 af = *(const short8*)(w1s + (size_t)(at * 16 + l15) * 416 + 384 + quad * 8);
      acc[at] = MFMA16(af, bf, acc[at]);
    }
  }

  // ---- epilogue: bias + lrelu, max over k (16 lanes of this wave's n) ----
  const int n = blockIdx.x * 4 + w;
  u16* orow = Xoutp + (size_t)(b * NN + n) * 64;
  #pragma unroll
  for (int at = 0; at < 4; ++at) {
    union { ushort4 v; u16 s[4]; } pk;
    #pragma unroll
    for (int r = 0; r < 4; ++r) {
      const int o = at * 16 + quad * 4 + r;
      float v = lrelu(acc[at][r] + bov[o] + bsv[o]);
      v = fmaxf(v, __shfl_xor(v, 1));
      v = fmaxf(v, __shfl_xor(v, 2));
      v = fmaxf(v, __shfl_xor(v, 4));
      v = fmaxf(v, __shfl_xor(v, 8));
      pk.s[r] = f2bf(v);
    }
    if (l15 == 0) *(ushort4*)(orow + at * 16 + quad * 4) = pk.v;
  }
}

// ---------------- edge conv (MFMA): gather, GEMM, lrelu, max over k ----------------
template<int CIN, int COUT>
__global__ __launch_bounds__(256) void conv_maxk_mfma(
    const u16* __restrict__ srcp, const int* __restrict__ idxb,
    const u16* __restrict__ wb, const float* __restrict__ bias,
    u16* __restrict__ Xoutp) {
  __shared__ __align__(16) u16 INs[64 * 32];
  __shared__ int nbrs[64];
  constexpr int CH = CIN / 2;

  const int t = threadIdx.x;
  const int b = blockIdx.z;
  const int p0 = blockIdx.x * 64;
  const int og0 = blockIdx.y * 64;
  const int w = t >> 6, l = t & 63;
  const int quad = l >> 4, l15 = l & 15;
  const int pl = w * 16 + l15;

  if (t < 64) nbrs[t] = idxb[b * NKP + p0 + t];
  __syncthreads();

  f32x4 acc[4];
  #pragma unroll
  for (int i = 0; i < 4; ++i) acc[i] = (f32x4)0.f;

  for (int c0 = 0; c0 < CIN; c0 += 32) {
    stage_gf<CH>(INs, srcp, nbrs, b, p0, c0, t);
    __syncthreads();
    const short8 bf = bfrag32(INs, pl, quad);
    #pragma unroll
    for (int at = 0; at < 4; ++at) {
      const short8 af = *(const short8*)(wb + (size_t)(og0 + at * 16 + l15) * CIN + c0 + quad * 8);
      acc[at] = MFMA16(af, bf, acc[at]);
    }
    __syncthreads();
  }

  const int n = blockIdx.x * 4 + w;
  u16* orow = Xoutp + (size_t)(b * NN + n) * COUT + og0;
  #pragma unroll
  for (int at = 0; at < 4; ++at) {
    union { ushort4 v; u16 s[4]; } pk;
    #pragma unroll
    for (int r = 0; r < 4; ++r) {
      float v = lrelu(acc[at][r] + bias[og0 + at * 16 + quad * 4 + r]);
      v = fmaxf(v, __shfl_xor(v, 1));
      v = fmaxf(v, __shfl_xor(v, 2));
      v = fmaxf(v, __shfl_xor(v, 4));
      v = fmaxf(v, __shfl_xor(v, 8));
      pk.s[r] = f2bf(v);
    }
    if (l15 == 0) *(ushort4*)(orow + at * 16 + quad * 4) = pk.v;
  }
}

// ---------------- conv5 (MFMA): concat inputs, 1024ch, partial max/sum over n ----------------
__global__ __launch_bounds__(256) void conv5_mfma(
    const u16* __restrict__ X1P, const u16* __restrict__ X2P,
    const u16* __restrict__ X3P, const u16* __restrict__ X4P,
    const u16* __restrict__ w5b, const float* __restrict__ b5,
    float* __restrict__ PMAX, float* __restrict__ PSUM) {
  __shared__ __align__(16) u16 INs[64 * 32];
  __shared__ float redm[4][64];
  __shared__ float reds[4][64];

  const int t = threadIdx.x;
  const int b = blockIdx.z;
  const int n0 = blockIdx.x * 64;
  const int og0 = blockIdx.y * 64;
  const int w = t >> 6, l = t & 63;
  const int quad = l >> 4, l15 = l & 15;
  const int pl = w * 16 + l15;

  f32x4 acc[4];
  #pragma unroll
  for (int i = 0; i < 4; ++i) acc[i] = (f32x4)0.f;

  for (int c0 = 0; c0 < 512; c0 += 32) {
    {
      const int p = t & 63, cq = t >> 6;
      const int c = c0 + cq * 8;
      const int n = n0 + p;
      const u16* src; int cc;
      if (c < 64)       { src = X1P + (size_t)(b * NN + n) * 64;  cc = c; }
      else if (c < 128) { src = X2P + (size_t)(b * NN + n) * 64;  cc = c - 64; }
      else if (c < 256) { src = X3P + (size_t)(b * NN + n) * 128; cc = c - 128; }
      else              { src = X4P + (size_t)(b * NN + n) * 256; cc = c - 256; }
      const uint4 val = *(const uint4*)(src + cc);
      const int pos = cq ^ (p & 3) ^ ((p >> 2) & 3);
      *(uint4*)(INs + p * 32 + pos * 8) = val;
    }
    __syncthreads();
    const short8 bf = bfrag32(INs, pl, quad);
    #pragma unroll
    for (int at = 0; at < 4; ++at) {
      const short8 af = *(const short8*)(w5b + (size_t)(og0 + at * 16 + l15) * 512 + c0 + quad * 8);
      acc[at] = MFMA16(af, bf, acc[at]);
    }
    __syncthreads();
  }

  #pragma unroll
  for (int at = 0; at < 4; ++at) {
    #pragma unroll
    for (int r = 0; r < 4; ++r) {
      const int o = at * 16 + quad * 4 + r;
      const float v = lrelu(acc[at][r] + b5[og0 + o]);
      float m = v, s = v;
      #pragma unroll
      for (int msk = 1; msk < 16; msk <<= 1) {
        m = fmaxf(m, __shfl_xor(m, msk));
        s += __shfl_xor(s, msk);
      }
      if (l15 == 0) { redm[w][o] = m; reds[w][o] = s; }
    }
  }
  __syncthreads();
  if (t < 64) {
    float m = fmaxf(fmaxf(redm[0][t], redm[1][t]), fmaxf(redm[2][t], redm[3][t]));
    float s = reds[0][t] + reds[1][t] + reds[2][t] + reds[3][t];
    PMAX[(size_t)(b * 16 + blockIdx.x) * 1024 + og0 + t] = m;
    PSUM[(size_t)(b * 16 + blockIdx.x) * 1024 + og0 + t] = s;
  }
}

__global__ __launch_bounds__(256) void reduce5(const float* __restrict__ PMAX, const float* __restrict__ PSUM,
                                               float* __restrict__ XPg) {
  const int tid = blockIdx.x * 256 + threadIdx.x;  // 8192
  const int b = tid >> 10, o = tid & 1023;
  float m = -INFINITY, s = 0.f;
  for (int pt = 0; pt < 16; ++pt) {
    m = fmaxf(m, PMAX[(size_t)(b * 16 + pt) * 1024 + o]);
    s += PSUM[(size_t)(b * 16 + pt) * 1024 + o];
  }
  XPg[b * 2048 + o] = m;
  XPg[b * 2048 + 1024 + o] = s * (1.f / 1024.f);
}

// ---------------- FC head (fp32, unchanged) ----------------
__global__ __launch_bounds__(256) void fc1_kernel(const float* __restrict__ XPg, const float* __restrict__ wl1t,
                                                  const float* __restrict__ bn4_b, float* __restrict__ XF1) {
  __shared__ float red[64 * 5];
  const int t = threadIdx.x;
  const int b = blockIdx.y;
  const int o = blockIdx.x * 64 + (t & 63);
  const int cq = t >> 6;
  const float* xp = XPg + b * 2048;
  float acc = 0.f;
  for (int c = cq * 512; c < cq * 512 + 512; ++c) acc = fmaf(wl1t[c * 512 + o], xp[c], acc);
  red[(t & 63) * 5 + cq] = acc;
  __syncthreads();
  if (t < 64) {
    const int oo = blockIdx.x * 64 + t;
    const float v = red[t * 5] + red[t * 5 + 1] + red[t * 5 + 2] + red[t * 5 + 3] + bn4_b[oo];
    XF1[b * 512 + oo] = lrelu(v);
  }
}

__global__ __launch_bounds__(256) void fc2_kernel(const float* __restrict__ XF1, const float* __restrict__ wl2t,
                                                  const float* __restrict__ bl2, const float* __restrict__ bn5_g,
                                                  const float* __restrict__ bn5_b, float* __restrict__ XF2) {
  __shared__ float red[64 * 5];
  const int t = threadIdx.x;
  const int b = blockIdx.y;
  const int o = blockIdx.x * 64 + (t & 63);
  const int cq = t >> 6;
  const float* xf = XF1 + b * 512;
  float acc = 0.f;
  for (int c = cq * 128; c < cq * 128 + 128; ++c) acc = fmaf(wl2t[c * 256 + o], xf[c], acc);
  red[(t & 63) * 5 + cq] = acc;
  __syncthreads();
  if (t < 64) {
    const int oo = blockIdx.x * 64 + t;
    const float bias = bl2[oo] * (bn5_g[oo] * BN_INV) + bn5_b[oo];
    const float v = red[t * 5] + red[t * 5 + 1] + red[t * 5 + 2] + red[t * 5 + 3] + bias;
    XF2[b * 256 + oo] = lrelu(v);
  }
}

__global__ __launch_bounds__(256) void fc3_kernel(const float* __restrict__ XF2, const float* __restrict__ wl3t,
                                                  const float* __restrict__ bl3, float* __restrict__ out) {
  __shared__ float red[64 * 5];
  const int t = threadIdx.x;
  const int b = blockIdx.y;
  const int ol = t & 63;
  const int cq = t >> 6;
  const float* xf = XF2 + b * 256;
  float acc = 0.f;
  if (ol < 49) for (int c = cq * 64; c < cq * 64 + 64; ++c) acc = fmaf(wl3t[c * 49 + ol], xf[c], acc);
  red[ol * 5 + cq] = acc;
  __syncthreads();
  if (t < 49) out[b * 49 + t] = red[t * 5] + red[t * 5 + 1] + red[t * 5 + 2] + red[t * 5 + 3] + bl3[t];
}

// ---------------- host ----------------
extern "C" void kernel_launch(void* const* d_in, const int* in_sizes, int n_in,
                              void* d_out, int out_size, void* d_ws, size_t ws_size,
                              hipStream_t stream) {
  (void)in_sizes; (void)n_in; (void)out_size; (void)ws_size;
  const float* x     = (const float*)d_in[0];
  const float* m1_w0 = (const float*)d_in[1];
  const float* m1_g0 = (const float*)d_in[2];
  const float* m1_b0 = (const float*)d_in[3];
  const float* m1_wm = (const float*)d_in[4];
  const float* m1_gm = (const float*)d_in[5];
  const float* m1_bm = (const float*)d_in[6];
  const float* m1_w1 = (const float*)d_in[7];
  const float* m1_go = (const float*)d_in[8];
  const float* m1_bo = (const float*)d_in[9];
  const float* m1_ws = (const float*)d_in[10];
  const float* m1_gs = (const float*)d_in[11];
  const float* m1_bs = (const float*)d_in[12];
  const float* m2_w0 = (const float*)d_in[13];
  const float* m2_g0 = (const float*)d_in[14];
  const float* m2_b0 = (const float*)d_in[15];
  const float* m2_wm = (const float*)d_in[16];
  const float* m2_gm = (const float*)d_in[17];
  const float* m2_bm = (const float*)d_in[18];
  const float* m2_w1 = (const float*)d_in[19];
  const float* m2_go = (const float*)d_in[20];
  const float* m2_bo = (const float*)d_in[21];
  const float* m2_ws = (const float*)d_in[22];
  const float* m2_gs = (const float*)d_in[23];
  const float* m2_bs = (const float*)d_in[24];
  const float* w3    = (const float*)d_in[25];
  const float* g3    = (const float*)d_in[26];
  const float* b3    = (const float*)d_in[27];
  const float* w4    = (const float*)d_in[28];
  const float* g4    = (const float*)d_in[29];
  const float* b4    = (const float*)d_in[30];
  const float* w5    = (const float*)d_in[31];
  const float* g5    = (const float*)d_in[32];
  const float* b5    = (const float*)d_in[33];
  const float* wl1   = (const float*)d_in[34];
  const float* bn4_g = (const float*)d_in[35];
  const float* bn4_b = (const float*)d_in[36];
  const float* wl2   = (const float*)d_in[37];
  const float* bl2   = (const float*)d_in[38];
  const float* bn5_g = (const float*)d_in[39];
  const float* bn5_b = (const float*)d_in[40];
  const float* wl3   = (const float*)d_in[41];
  const float* bl3   = (const float*)d_in[42];

  char* wsb = (char*)d_ws;
  int*  IDX  = (int*)(wsb + OFF_IDX);
  u16*  X1P  = (u16*)(wsb + OFF_X1P);
  u16*  X2P  = (u16*)(wsb + OFF_X2P);
  u16*  X3P  = (u16*)(wsb + OFF_X3P);
  u16*  X4P  = (u16*)(wsb + OFF_X4P);
  float* PMAX = (float*)(wsb + OFF_PMAX);
  float* PSUM = (float*)(wsb + OFF_PSUM);
  float* XPg  = (float*)(wsb + OFF_XP);
  float* XF1  = (float*)(wsb + OFF_XF1);
  float* XF2  = (float*)(wsb + OFF_XF2);
  u16*  M1W0 = (u16*)(wsb + OFF_M1W0);
  u16*  M1WM = (u16*)(wsb + OFF_M1WM);
  u16*  M1W1S = (u16*)(wsb + OFF_M1W1S);
  u16*  M2W0 = (u16*)(wsb + OFF_M2W0);
  u16*  M2WM = (u16*)(wsb + OFF_M2WM);
  u16*  M2W1S = (u16*)(wsb + OFF_M2W1S);
  u16*  W3B  = (u16*)(wsb + OFF_W3);
  u16*  W4B  = (u16*)(wsb + OFF_W4);
  u16*  W5B  = (u16*)(wsb + OFF_W5);
  float* WL1T = (float*)(wsb + OFF_WL1T);
  float* WL2T = (float*)(wsb + OFF_WL2T);
  float* WL3T = (float*)(wsb + OFF_WL3T);

  // bf16 weight prep with gamma fold
  SArgs sa; int st = 0;
  auto sset = [&](int i, const float* w, const float* g, u16* dst, int O, int C, int cpl2) {
    sa.seg[i].w = w; sa.seg[i].g = g; sa.seg[i].dst = dst; sa.seg[i].C = C;
    sa.seg[i].cpl2 = cpl2; sa.seg[i].start = st; st += O << cpl2;
  };
  sset(0, m1_w0, m1_g0, M1W0, 64, 6, 5);
  sset(1, m1_wm, m1_gm, M1WM, 64, 64, 6);
  sset(2, m2_w0, m2_g0, M2W0, 64, 128, 7);
  sset(3, m2_wm, m2_gm, M2WM, 64, 64, 6);
  sset(4, w3, g3, W3B, 128, 128, 7);
  sset(5, w4, g4, W4B, 256, 256, 8);
  sset(6, w5, g5, W5B, 1024, 512, 9);
  sa.total = st;  // 624640

  TArgs3 ta; int tt = 0;
  auto tset = [&](int i, const float* w, const float* g, float* dst, int O, int C) {
    ta.seg[i].w = w; ta.seg[i].g = g; ta.seg[i].dst = dst; ta.seg[i].O = O; ta.seg[i].C = C;
    ta.seg[i].start = tt; tt += O * C;
  };
  tset(0, wl1, bn4_g, WL1T, 512, 2048);
  tset(1, wl2, bn5_g, WL2T, 256, 512);
  tset(2, wl3, nullptr, WL3T, 49, 256);
  ta.total = tt;  // 1192192

  hipLaunchKernelGGL(prep_scale_bf16, dim3((sa.total + 255) / 256), dim3(256), 0, stream, sa);
  hipLaunchKernelGGL(prep_w1s_bf16, dim3(104), dim3(256), 0, stream, m1_w1, m1_ws, m1_go, m1_gs, M1W1S);
  hipLaunchKernelGGL(prep_w1s_bf16, dim3(104), dim3(256), 0, stream, m2_w1, m2_ws, m2_go, m2_gs, M2W1S);
  hipLaunchKernelGGL(prep_transpose_f32, dim3((ta.total + 255) / 256), dim3(256), 0, stream, ta);

  hipLaunchKernelGGL(knn_kernel, dim3(2048), dim3(256), 0, stream, x, IDX);

  hipLaunchKernelGGL((mak_mfma<6>), dim3(256, 1, BB), dim3(256), 0, stream,
                     x, IDX, (const u16*)nullptr, M1W0, m1_b0, M1WM, m1_bm, M1W1S, m1_bo, m1_bs, X1P);
  hipLaunchKernelGGL((mak_mfma<128>), dim3(256, 1, BB), dim3(256), 0, stream,
                     x, IDX, X1P, M2W0, m2_b0, M2WM, m2_bm, M2W1S, m2_bo, m2_bs, X2P);

  hipLaunchKernelGGL((conv_maxk_mfma<128, 128>), dim3(256, 2, BB), dim3(256), 0, stream,
                     X2P, IDX, W3B, b3, X3P);
  hipLaunchKernelGGL((conv_maxk_mfma<256, 256>), dim3(256, 4, BB), dim3(256), 0, stream,
                     X3P, IDX, W4B, b4, X4P);

  hipLaunchKernelGGL(conv5_mfma, dim3(16, 16, BB), dim3(256), 0, stream,
                     X1P, X2P, X3P, X4P, W5B, b5, PMAX, PSUM);
  hipLaunchKernelGGL(reduce5, dim3(32), dim3(256), 0, stream, PMAX, PSUM, XPg);

  hipLaunchKernelGGL(fc1_kernel, dim3(8, BB), dim3(256), 0, stream, XPg, WL1T, bn4_b, XF1);
  hipLaunchKernelGGL(fc2_kernel, dim3(4, BB), dim3(256), 0, stream, XF1, WL2T, bl2, bn5_g, bn5_b, XF2);
  hipLaunchKernelGGL(fc3_kernel, dim3(1, BB), dim3(256), 0, stream, XF2, WL3T, bl3, (float*)d_out);
}

// Round 3
// 484.944 us; speedup vs baseline: 2.2074x; 1.2750x over previous
//
#include <hip/hip_runtime.h>
#include <math.h>

#define BB 8
#define NN 1024
#define KK 16
#define NKP (NN*KK)
#define BN_INV 0.99999500003749981f

typedef unsigned short u16;
typedef __attribute__((ext_vector_type(8))) short short8;
typedef __attribute__((ext_vector_type(4))) float f32x4;

#define MFMA16(a,b,c) __builtin_amdgcn_mfma_f32_16x16x32_bf16(a,b,c,0,0,0)

__device__ __forceinline__ float lrelu(float v) { return v >= 0.f ? v : 0.2f * v; }

__device__ __forceinline__ u16 f2bf(float f) {
  union { float f; unsigned u; } v; v.f = f;
  unsigned r = v.u + 0x7fff + ((v.u >> 16) & 1);
  return (u16)(r >> 16);
}
__device__ __forceinline__ float bf2f(u16 s) {
  union { unsigned u; float f; } v; v.u = ((unsigned)s) << 16;
  return v.f;
}

// ---------------- workspace byte offsets ----------------
constexpr size_t OFF_IDX   = 0;          // int[8*1024*16]
constexpr size_t OFF_X1P   = 524288;     // bf16 [8][1024][64]
constexpr size_t OFF_X2P   = 1572864;
constexpr size_t OFF_X3P   = 2621440;    // bf16 [8][1024][128]
constexpr size_t OFF_X4P   = 4718592;    // bf16 [8][1024][256]
constexpr size_t OFF_PMAX  = 8912896;    // f32 [8][16][1024]
constexpr size_t OFF_PSUM  = 9437184;
constexpr size_t OFF_XP    = 9961472;    // f32 [8][2048]
constexpr size_t OFF_XF1   = 10027008;   // f32 [8][512]
constexpr size_t OFF_XF2   = 10043392;   // f32 [8][256]
constexpr size_t OFF_M1W0  = 10051584;   // bf16 [64][32] (6 real, pad 0)
constexpr size_t OFF_M1WM  = 10055680;   // bf16 [64][64]
constexpr size_t OFF_M1W1S = 10063872;   // bf16 [64][416]
constexpr size_t OFF_M2W0  = 10117120;   // bf16 [64][128]
constexpr size_t OFF_M2WM  = 10133504;   // bf16 [64][64]
constexpr size_t OFF_M2W1S = 10141696;   // bf16 [64][416]
constexpr size_t OFF_W3    = 10194944;   // bf16 [128][128]
constexpr size_t OFF_W4    = 10227712;   // bf16 [256][256]
constexpr size_t OFF_W5    = 10358784;   // bf16 [1024][512]
constexpr size_t OFF_WL1T  = 11407360;   // f32 [2048][512]
constexpr size_t OFF_WL2T  = 15601664;   // f32 [512][256]
constexpr size_t OFF_WL3T  = 16125952;   // f32 [256][49]

// ---------------- weight prep ----------------
struct SSeg { const float* w; const float* g; u16* dst; int C; int cpl2; int start; };
struct SArgs { SSeg seg[7]; int total; };

__global__ __launch_bounds__(256) void prep_scale_bf16(SArgs a) {
  const int tid = blockIdx.x * 256 + threadIdx.x;
  if (tid >= a.total) return;
  int s = 0;
  #pragma unroll
  for (int i = 1; i < 7; ++i) if (tid >= a.seg[i].start) s = i;
  const SSeg sg = a.seg[s];
  const int e = tid - sg.start;
  const int o = e >> sg.cpl2;
  const int c = e & ((1 << sg.cpl2) - 1);
  float v = 0.f;
  if (c < sg.C) v = sg.w[o * sg.C + c] * sg.g[o] * BN_INV;
  sg.dst[e] = f2bf(v);
}

__global__ __launch_bounds__(256) void prep_w1s_bf16(const float* __restrict__ w1, const float* __restrict__ wsm,
                                                     const float* __restrict__ go, const float* __restrict__ gs,
                                                     u16* __restrict__ dst) {
  const int tid = blockIdx.x * 256 + threadIdx.x;
  if (tid >= 64 * 416) return;
  const int o = tid / 416, ci = tid - o * 416;
  float v = 0.f;
  if (ci < 384) {
    const int ii = ci >> 6, ch = ci & 63;
    const int base = (o * 24 + ii * 4) * 64 + ch;
    v = go[o] * BN_INV * (w1[base] + w1[base + 64] + w1[base + 128] + w1[base + 192]);
  } else if (ci < 390) {
    v = gs[o] * BN_INV * wsm[o * 6 + (ci - 384)];
  }
  dst[tid] = f2bf(v);
}

struct TSeg { const float* w; const float* g; float* dst; int O; int C; int start; };
struct TArgs3 { TSeg seg[3]; int total; };

__global__ __launch_bounds__(256) void prep_transpose_f32(TArgs3 a) {
  const int tid = blockIdx.x * 256 + threadIdx.x;
  if (tid >= a.total) return;
  int s = 0;
  #pragma unroll
  for (int i = 1; i < 3; ++i) if (tid >= a.seg[i].start) s = i;
  const TSeg sg = a.seg[s];
  const int e = tid - sg.start;
  const int c = e / sg.O;
  const int o = e - c * sg.O;
  float v = sg.w[o * sg.C + c];
  if (sg.g) v *= sg.g[o] * BN_INV;
  sg.dst[e] = v;
}

// ---------------- KNN (exact fp32) ----------------
__global__ __launch_bounds__(256) void knn_kernel(const float* __restrict__ x, int* __restrict__ idxout) {
  const int wid  = (blockIdx.x * blockDim.x + threadIdx.x) >> 6;
  const int lane = threadIdx.x & 63;
  const int b = wid >> 10;
  const int n = wid & (NN - 1);
  const float* xb = x + b * 3 * NN;
  const float x0n = xb[n], x1n = xb[NN + n], x2n = xb[2 * NN + n];
  const float xxn = x0n * x0n + x1n * x1n + x2n * x2n;
  float pd[16];
  #pragma unroll
  for (int j = 0; j < 16; ++j) {
    const int m = j * 64 + lane;
    const float x0 = xb[m], x1 = xb[NN + m], x2 = xb[2 * NN + m];
    const float dot = x0n * x0 + x1n * x1 + x2n * x2;
    const float xxm = x0 * x0 + x1 * x1 + x2 * x2;
    pd[j] = 2.f * dot - xxn - xxm;
  }
  for (int r = 0; r < 16; ++r) {
    float bv = pd[0]; int bj = 0;
    #pragma unroll
    for (int j = 1; j < 16; ++j) if (pd[j] > bv) { bv = pd[j]; bj = j; }
    int bm = bj * 64 + lane;
    #pragma unroll
    for (int off = 32; off > 0; off >>= 1) {
      const float ov = __shfl_down(bv, off);
      const int   om = __shfl_down(bm, off);
      if (ov > bv || (ov == bv && om < bm)) { bv = ov; bm = om; }
    }
    bm = __shfl(bm, 0);
    if (lane == 0) idxout[wid * KK + r] = bm;
    const int  cj   = bm >> 6;
    const bool mine = (bm & 63) == lane;
    #pragma unroll
    for (int j = 0; j < 16; ++j) if (mine && j == cj) pd[j] = -INFINITY;
  }
}

// ---------------- MFMA helpers ----------------
__device__ __forceinline__ short8 bfrag32(const u16* INs, int pl, int quad) {
  const int pos = quad ^ (pl & 3) ^ ((pl >> 2) & 3);
  return *(const short8*)(INs + pl * 32 + pos * 8);
}
__device__ __forceinline__ short8 bfrag64(const u16* T, int pl, int quad, int c0) {
  const int pos = ((c0 >> 3) + quad) ^ (pl & 7);
  return *(const short8*)(T + pl * 64 + pos * 8);
}

__device__ __forceinline__ uint4 diff8(uint4 qa, uint4 qb) {
  union { uint4 q; u16 s[8]; } ua, ub, r;
  ua.q = qa; ub.q = qb;
  #pragma unroll
  for (int j = 0; j < 8; ++j) r.s[j] = f2bf(bf2f(ua.s[j]) - bf2f(ub.s[j]));
  return r.q;
}

__device__ __forceinline__ void writeD64(u16* T, int pl, int quad, const f32x4 a,
                                         const float* __restrict__ bias, int obase) {
  union { ushort4 v; u16 s[4]; } pk;
  #pragma unroll
  for (int r = 0; r < 4; ++r) pk.s[r] = f2bf(lrelu(a[r] + bias[obase + quad * 4 + r]));
  const int g = (obase + quad * 4) >> 3;
  const int pos = g ^ (pl & 7);
  *(ushort4*)(T + pl * 64 + pos * 8 + (quad & 1) * 4) = pk.v;
}

// ---------------- fused mak block (MFMA) ----------------
template<int CIN_Y>
__global__ __launch_bounds__(256) void mak_mfma(
    const float* __restrict__ x, const int* __restrict__ idxb, const u16* __restrict__ srcp,
    const u16* __restrict__ w0b, const float* __restrict__ b0v,
    const u16* __restrict__ wmb, const float* __restrict__ bmv,
    const u16* __restrict__ w1s, const float* __restrict__ bov, const float* __restrict__ bsv,
    u16* __restrict__ Xoutp) {
  __shared__ __align__(16) u16 GEOs[64 * 32];
  __shared__ __align__(16) u16 Y0s[64 * 64];
  __shared__ __align__(16) u16 YMs[64 * 64];
  __shared__ __align__(16) u16 INs[2][64 * 32];
  __shared__ int nbrs[64];

  const int t = threadIdx.x;
  const int b = blockIdx.z;
  const int p0 = blockIdx.x * 64;
  const int w = t >> 6, l = t & 63;
  const int quad = l >> 4, l15 = l & 15;
  const int pl = w * 16 + l15;

  if (t < 64) nbrs[t] = idxb[b * NKP + p0 + t];
  __syncthreads();

  // stage geo [64p][32c]
  const float* xb = x + b * 3 * NN;
  const int p = t & 63, cq = t >> 6;
  {
    const int n = (p0 + p) >> 4;
    union { uint4 q; u16 s[8]; } val;
    #pragma unroll
    for (int j = 0; j < 8; ++j) {
      const int c = cq * 8 + j;
      float v = 0.f;
      if (c < 3)      v = xb[c * NN + nbrs[p]] - xb[c * NN + n];
      else if (c < 6) v = xb[(c - 3) * NN + n];
      val.s[j] = f2bf(v);
    }
    const int pos = cq ^ (p & 3) ^ ((p >> 2) & 3);
    *(uint4*)(GEOs + p * 32 + pos * 8) = val.q;
  }

  f32x4 acc[4];
  #pragma unroll
  for (int i = 0; i < 4; ++i) acc[i] = (f32x4)0.f;

  // ---- GEMM1 ----
  if constexpr (CIN_Y == 6) {
    __syncthreads();
    const short8 bf = bfrag32(GEOs, pl, quad);
    #pragma unroll
    for (int at = 0; at < 4; ++at) {
      const short8 af = *(const short8*)(w0b + (size_t)(at * 16 + l15) * 32 + quad * 8);
      acc[at] = MFMA16(af, bf, acc[at]);
    }
  } else {
    constexpr int CH = CIN_Y / 2;
    uint4 va, vb; bool isdiff = false;
    auto pf = [&](int c0) {
      const int c = c0 + cq * 8;
      const int n = (p0 + p) >> 4;
      isdiff = (c < CH);
      if (isdiff) {
        va = *(const uint4*)(srcp + ((size_t)(b * NN + nbrs[p]) * CH + c));
        vb = *(const uint4*)(srcp + ((size_t)(b * NN + n) * CH + c));
      } else {
        va = *(const uint4*)(srcp + ((size_t)(b * NN + n) * CH + (c - CH)));
      }
    };
    pf(0);
    const int pos = cq ^ (p & 3) ^ ((p >> 2) & 3);
    for (int k = 0; k < CIN_Y / 32; ++k) {
      const uint4 val = isdiff ? diff8(va, vb) : va;
      *(uint4*)(INs[k & 1] + p * 32 + pos * 8) = val;
      if (k + 1 < CIN_Y / 32) pf((k + 1) * 32);
      __syncthreads();
      const short8 bf = bfrag32(INs[k & 1], pl, quad);
      #pragma unroll
      for (int at = 0; at < 4; ++at) {
        const short8 af = *(const short8*)(w0b + (size_t)(at * 16 + l15) * CIN_Y + k * 32 + quad * 8);
        acc[at] = MFMA16(af, bf, acc[at]);
      }
    }
  }
  #pragma unroll
  for (int at = 0; at < 4; ++at) writeD64(Y0s, pl, quad, acc[at], b0v, at * 16);
  __syncthreads();

  // ---- GEMM2: 64 -> 64 ----
  #pragma unroll
  for (int i = 0; i < 4; ++i) acc[i] = (f32x4)0.f;
  #pragma unroll
  for (int c0 = 0; c0 < 64; c0 += 32) {
    const short8 bf = bfrag64(Y0s, pl, quad, c0);
    #pragma unroll
    for (int at = 0; at < 4; ++at) {
      const short8 af = *(const short8*)(wmb + (size_t)(at * 16 + l15) * 64 + c0 + quad * 8);
      acc[at] = MFMA16(af, bf, acc[at]);
    }
  }
  #pragma unroll
  for (int at = 0; at < 4; ++at) writeD64(YMs, pl, quad, acc[at], bmv, at * 16);
  __syncthreads();

  // ---- GEMM3: 384 virtual channels, B-frag built in registers (no staging, no syncs) ----
  #pragma unroll
  for (int i = 0; i < 4; ++i) acc[i] = (f32x4)0.f;
  const int posg = (pl & 3) ^ ((pl >> 2) & 3);
  #pragma unroll
  for (int k = 0; k < 12; ++k) {
    const int ii = k >> 1, ch0 = (k & 1) * 32;
    union { short8 v; u16 s[8]; } ym, bfv;
    ym.v = bfrag64(YMs, pl, quad, ch0);
    const float ge = bf2f(GEOs[pl * 32 + posg * 8 + ii]);
    #pragma unroll
    for (int j = 0; j < 8; ++j) bfv.s[j] = f2bf(bf2f(ym.s[j]) * ge);
    #pragma unroll
    for (int at = 0; at < 4; ++at) {
      const short8 af = *(const short8*)(w1s + (size_t)(at * 16 + l15) * 416 + k * 32 + quad * 8);
      acc[at] = MFMA16(af, bfv.v, acc[at]);
    }
  }
  {  // idt chunk: B = geo tile
    const short8 bf = bfrag32(GEOs, pl, quad);
    #pragma unroll
    for (int at = 0; at < 4; ++at) {
      const short8 af = *(const short8*)(w1s + (size_t)(at * 16 + l15) * 416 + 384 + quad * 8);
      acc[at] = MFMA16(af, bf, acc[at]);
    }
  }

  // ---- epilogue: bias + lrelu, max over k=l15 ----
  const int n = blockIdx.x * 4 + w;
  u16* orow = Xoutp + (size_t)(b * NN + n) * 64;
  #pragma unroll
  for (int at = 0; at < 4; ++at) {
    union { ushort4 v; u16 s[4]; } pk;
    #pragma unroll
    for (int r = 0; r < 4; ++r) {
      const int o = at * 16 + quad * 4 + r;
      float v = lrelu(acc[at][r] + bov[o] + bsv[o]);
      v = fmaxf(v, __shfl_xor(v, 1));
      v = fmaxf(v, __shfl_xor(v, 2));
      v = fmaxf(v, __shfl_xor(v, 4));
      v = fmaxf(v, __shfl_xor(v, 8));
      pk.s[r] = f2bf(v);
    }
    if (l15 == 0) *(ushort4*)(orow + at * 16 + quad * 4) = pk.v;
  }
}

// ---------------- edge conv (MFMA): all COUT per block, waves split o, double-buffered ----------------
template<int CIN, int COUT>
__global__ __launch_bounds__(256) void conv_maxk_mfma(
    const u16* __restrict__ srcp, const int* __restrict__ idxb,
    const u16* __restrict__ wb, const float* __restrict__ bias,
    u16* __restrict__ Xoutp) {
  __shared__ __align__(16) u16 INs[2][64 * 32];
  __shared__ int nbrs[64];
  constexpr int CH = CIN / 2;
  constexpr int OPW = COUT / 4;   // outs per wave
  constexpr int NAT = OPW / 16;   // o-tiles per wave

  const int t = threadIdx.x;
  const int b = blockIdx.z;
  const int p0 = blockIdx.x * 64;
  const int w = t >> 6, l = t & 63;
  const int quad = l >> 4, l15 = l & 15;
  const int ow0 = w * OPW;

  if (t < 64) nbrs[t] = idxb[b * NKP + p0 + t];
  __syncthreads();

  f32x4 acc[NAT][4];
  #pragma unroll
  for (int i = 0; i < NAT; ++i)
    #pragma unroll
    for (int j = 0; j < 4; ++j) acc[i][j] = (f32x4)0.f;

  const int p = t & 63, cq = t >> 6;
  const int pos = cq ^ (p & 3) ^ ((p >> 2) & 3);
  uint4 va, vb; bool isdiff = false;
  auto pf = [&](int c0) {
    const int c = c0 + cq * 8;
    const int n = (p0 + p) >> 4;
    isdiff = (c < CH);
    if (isdiff) {
      va = *(const uint4*)(srcp + ((size_t)(b * NN + nbrs[p]) * CH + c));
      vb = *(const uint4*)(srcp + ((size_t)(b * NN + n) * CH + c));
    } else {
      va = *(const uint4*)(srcp + ((size_t)(b * NN + n) * CH + (c - CH)));
    }
  };
  pf(0);
  for (int k = 0; k < CIN / 32; ++k) {
    const uint4 val = isdiff ? diff8(va, vb) : va;
    *(uint4*)(INs[k & 1] + p * 32 + pos * 8) = val;
    if (k + 1 < CIN / 32) pf((k + 1) * 32);
    __syncthreads();
    short8 bfr[4];
    #pragma unroll
    for (int pg = 0; pg < 4; ++pg) bfr[pg] = bfrag32(INs[k & 1], pg * 16 + l15, quad);
    #pragma unroll
    for (int at = 0; at < NAT; ++at) {
      const short8 af = *(const short8*)(wb + (size_t)(ow0 + at * 16 + l15) * CIN + k * 32 + quad * 8);
      #pragma unroll
      for (int pg = 0; pg < 4; ++pg) acc[at][pg] = MFMA16(af, bfr[pg], acc[at][pg]);
    }
  }

  // epilogue: p = pg*16 + l15 -> n_local = pg, k = l15; reduce over l15
  #pragma unroll
  for (int pg = 0; pg < 4; ++pg) {
    const int n = blockIdx.x * 4 + pg;
    u16* orow = Xoutp + (size_t)(b * NN + n) * COUT + ow0;
    #pragma unroll
    for (int at = 0; at < NAT; ++at) {
      union { ushort4 v; u16 s[4]; } pk;
      #pragma unroll
      for (int r = 0; r < 4; ++r) {
        float v = lrelu(acc[at][pg][r] + bias[ow0 + at * 16 + quad * 4 + r]);
        v = fmaxf(v, __shfl_xor(v, 1));
        v = fmaxf(v, __shfl_xor(v, 2));
        v = fmaxf(v, __shfl_xor(v, 4));
        v = fmaxf(v, __shfl_xor(v, 8));
        pk.s[r] = f2bf(v);
      }
      if (l15 == 0) *(ushort4*)(orow + at * 16 + quad * 4) = pk.v;
    }
  }
}

// ---------------- conv5 (MFMA): 64n x 256o per block, waves split o, double-buffered ----------------
__global__ __launch_bounds__(256) void conv5_mfma(
    const u16* __restrict__ X1P, const u16* __restrict__ X2P,
    const u16* __restrict__ X3P, const u16* __restrict__ X4P,
    const u16* __restrict__ w5b, const float* __restrict__ b5,
    float* __restrict__ PMAX, float* __restrict__ PSUM) {
  __shared__ __align__(16) u16 INs[2][64 * 32];

  const int t = threadIdx.x;
  const int b = blockIdx.z;
  const int n0 = blockIdx.x * 64;
  const int w = t >> 6, l = t & 63;
  const int quad = l >> 4, l15 = l & 15;
  const int ow0 = blockIdx.y * 256 + w * 64;

  f32x4 acc[4][4];
  #pragma unroll
  for (int i = 0; i < 4; ++i)
    #pragma unroll
    for (int j = 0; j < 4; ++j) acc[i][j] = (f32x4)0.f;

  const int p = t & 63, cq = t >> 6;
  const int pos = cq ^ (p & 3) ^ ((p >> 2) & 3);
  uint4 pfv;
  auto pf = [&](int c0) {
    const int c = c0 + cq * 8;
    const int n = n0 + p;
    const u16* src; int cc;
    if (c < 64)       { src = X1P + (size_t)(b * NN + n) * 64;  cc = c; }
    else if (c < 128) { src = X2P + (size_t)(b * NN + n) * 64;  cc = c - 64; }
    else if (c < 256) { src = X3P + (size_t)(b * NN + n) * 128; cc = c - 128; }
    else              { src = X4P + (size_t)(b * NN + n) * 256; cc = c - 256; }
    pfv = *(const uint4*)(src + cc);
  };
  pf(0);
  for (int k = 0; k < 16; ++k) {
    *(uint4*)(INs[k & 1] + p * 32 + pos * 8) = pfv;
    if (k < 15) pf((k + 1) * 32);
    __syncthreads();
    short8 bfr[4];
    #pragma unroll
    for (int pg = 0; pg < 4; ++pg) bfr[pg] = bfrag32(INs[k & 1], pg * 16 + l15, quad);
    #pragma unroll
    for (int at = 0; at < 4; ++at) {
      const short8 af = *(const short8*)(w5b + (size_t)(ow0 + at * 16 + l15) * 512 + k * 32 + quad * 8);
      #pragma unroll
      for (int pg = 0; pg < 4; ++pg) acc[at][pg] = MFMA16(af, bfr[pg], acc[at][pg]);
    }
  }

  // epilogue: reduce over all 64 n (pg in regs, l15 via shuffle); wave-private o's
  #pragma unroll
  for (int at = 0; at < 4; ++at) {
    f32x4 pmx, psm;
    #pragma unroll
    for (int r = 0; r < 4; ++r) {
      const int o = ow0 + at * 16 + quad * 4 + r;
      const float bb = b5[o];
      float m = -INFINITY, s = 0.f;
      #pragma unroll
      for (int pg = 0; pg < 4; ++pg) {
        const float v = lrelu(acc[at][pg][r] + bb);
        m = fmaxf(m, v); s += v;
      }
      #pragma unroll
      for (int msk = 1; msk < 16; msk <<= 1) {
        m = fmaxf(m, __shfl_xor(m, msk));
        s += __shfl_xor(s, msk);
      }
      pmx[r] = m; psm[r] = s;
    }
    if (l15 == 0) {
      float* dm = PMAX + (size_t)(b * 16 + blockIdx.x) * 1024 + ow0 + at * 16 + quad * 4;
      float* ds = PSUM + (size_t)(b * 16 + blockIdx.x) * 1024 + ow0 + at * 16 + quad * 4;
      *(f32x4*)dm = pmx;
      *(f32x4*)ds = psm;
    }
  }
}

__global__ __launch_bounds__(256) void reduce5(const float* __restrict__ PMAX, const float* __restrict__ PSUM,
                                               float* __restrict__ XPg) {
  const int tid = blockIdx.x * 256 + threadIdx.x;  // 8192
  const int b = tid >> 10, o = tid & 1023;
  float m = -INFINITY, s = 0.f;
  for (int pt = 0; pt < 16; ++pt) {
    m = fmaxf(m, PMAX[(size_t)(b * 16 + pt) * 1024 + o]);
    s += PSUM[(size_t)(b * 16 + pt) * 1024 + o];
  }
  XPg[b * 2048 + o] = m;
  XPg[b * 2048 + 1024 + o] = s * (1.f / 1024.f);
}

// ---------------- FC head ----------------
__global__ __launch_bounds__(256) void fc1_kernel(const float* __restrict__ XPg, const float* __restrict__ wl1t,
                                                  const float* __restrict__ bn4_b, float* __restrict__ XF1) {
  __shared__ float red[64 * 5];
  const int t = threadIdx.x;
  const int b = blockIdx.y;
  const int o = blockIdx.x * 64 + (t & 63);
  const int cq = t >> 6;
  const float* xp = XPg + b * 2048;
  float acc = 0.f;
  for (int c = cq * 512; c < cq * 512 + 512; ++c) acc = fmaf(wl1t[c * 512 + o], xp[c], acc);
  red[(t & 63) * 5 + cq] = acc;
  __syncthreads();
  if (t < 64) {
    const int oo = blockIdx.x * 64 + t;
    const float v = red[t * 5] + red[t * 5 + 1] + red[t * 5 + 2] + red[t * 5 + 3] + bn4_b[oo];
    XF1[b * 512 + oo] = lrelu(v);
  }
}

__global__ __launch_bounds__(256) void fc2_kernel(const float* __restrict__ XF1, const float* __restrict__ wl2t,
                                                  const float* __restrict__ bl2, const float* __restrict__ bn5_g,
                                                  const float* __restrict__ bn5_b, float* __restrict__ XF2) {
  __shared__ float red[64 * 5];
  const int t = threadIdx.x;
  const int b = blockIdx.y;
  const int o = blockIdx.x * 64 + (t & 63);
  const int cq = t >> 6;
  const float* xf = XF1 + b * 512;
  float acc = 0.f;
  for (int c = cq * 128; c < cq * 128 + 128; ++c) acc = fmaf(wl2t[c * 256 + o], xf[c], acc);
  red[(t & 63) * 5 + cq] = acc;
  __syncthreads();
  if (t < 64) {
    const int oo = blockIdx.x * 64 + t;
    const float bias = bl2[oo] * (bn5_g[oo] * BN_INV) + bn5_b[oo];
    const float v = red[t * 5] + red[t * 5 + 1] + red[t * 5 + 2] + red[t * 5 + 3] + bias;
    XF2[b * 256 + oo] = lrelu(v);
  }
}

__global__ __launch_bounds__(256) void fc3_kernel(const float* __restrict__ XF2, const float* __restrict__ wl3t,
                                                  const float* __restrict__ bl3, float* __restrict__ out) {
  __shared__ float red[64 * 5];
  const int t = threadIdx.x;
  const int b = blockIdx.y;
  const int ol = t & 63;
  const int cq = t >> 6;
  const float* xf = XF2 + b * 256;
  float acc = 0.f;
  if (ol < 49) for (int c = cq * 64; c < cq * 64 + 64; ++c) acc = fmaf(wl3t[c * 49 + ol], xf[c], acc);
  red[ol * 5 + cq] = acc;
  __syncthreads();
  if (t < 49) out[b * 49 + t] = red[t * 5] + red[t * 5 + 1] + red[t * 5 + 2] + red[t * 5 + 3] + bl3[t];
}

// ---------------- host ----------------
extern "C" void kernel_launch(void* const* d_in, const int* in_sizes, int n_in,
                              void* d_out, int out_size, void* d_ws, size_t ws_size,
                              hipStream_t stream) {
  (void)in_sizes; (void)n_in; (void)out_size; (void)ws_size;
  const float* x     = (const float*)d_in[0];
  const float* m1_w0 = (const float*)d_in[1];
  const float* m1_g0 = (const float*)d_in[2];
  const float* m1_b0 = (const float*)d_in[3];
  const float* m1_wm = (const float*)d_in[4];
  const float* m1_gm = (const float*)d_in[5];
  const float* m1_bm = (const float*)d_in[6];
  const float* m1_w1 = (const float*)d_in[7];
  const float* m1_go = (const float*)d_in[8];
  const float* m1_bo = (const float*)d_in[9];
  const float* m1_ws = (const float*)d_in[10];
  const float* m1_gs = (const float*)d_in[11];
  const float* m1_bs = (const float*)d_in[12];
  const float* m2_w0 = (const float*)d_in[13];
  const float* m2_g0 = (const float*)d_in[14];
  const float* m2_b0 = (const float*)d_in[15];
  const float* m2_wm = (const float*)d_in[16];
  const float* m2_gm = (const float*)d_in[17];
  const float* m2_bm = (const float*)d_in[18];
  const float* m2_w1 = (const float*)d_in[19];
  const float* m2_go = (const float*)d_in[20];
  const float* m2_bo = (const float*)d_in[21];
  const float* m2_ws = (const float*)d_in[22];
  const float* m2_gs = (const float*)d_in[23];
  const float* m2_bs = (const float*)d_in[24];
  const float* w3    = (const float*)d_in[25];
  const float* g3    = (const float*)d_in[26];
  const float* b3    = (const float*)d_in[27];
  const float* w4    = (const float*)d_in[28];
  const float* g4    = (const float*)d_in[29];
  const float* b4    = (const float*)d_in[30];
  const float* w5    = (const float*)d_in[31];
  const float* g5    = (const float*)d_in[32];
  const float* b5    = (const float*)d_in[33];
  const float* wl1   = (const float*)d_in[34];
  const float* bn4_g = (const float*)d_in[35];
  const float* bn4_b = (const float*)d_in[36];
  const float* wl2   = (const float*)d_in[37];
  const float* bl2   = (const float*)d_in[38];
  const float* bn5_g = (const float*)d_in[39];
  const float* bn5_b = (const float*)d_in[40];
  const float* wl3   = (const float*)d_in[41];
  const float* bl3   = (const float*)d_in[42];

  char* wsb = (char*)d_ws;
  int*  IDX  = (int*)(wsb + OFF_IDX);
  u16*  X1P  = (u16*)(wsb + OFF_X1P);
  u16*  X2P  = (u16*)(wsb + OFF_X2P);
  u16*  X3P  = (u16*)(wsb + OFF_X3P);
  u16*  X4P  = (u16*)(wsb + OFF_X4P);
  float* PMAX = (float*)(wsb + OFF_PMAX);
  float* PSUM = (float*)(wsb + OFF_PSUM);
  float* XPg  = (float*)(wsb + OFF_XP);
  float* XF1  = (float*)(wsb + OFF_XF1);
  float* XF2  = (float*)(wsb + OFF_XF2);
  u16*  M1W0 = (u16*)(wsb + OFF_M1W0);
  u16*  M1WM = (u16*)(wsb + OFF_M1WM);
  u16*  M1W1S = (u16*)(wsb + OFF_M1W1S);
  u16*  M2W0 = (u16*)(wsb + OFF_M2W0);
  u16*  M2WM = (u16*)(wsb + OFF_M2WM);
  u16*  M2W1S = (u16*)(wsb + OFF_M2W1S);
  u16*  W3B  = (u16*)(wsb + OFF_W3);
  u16*  W4B  = (u16*)(wsb + OFF_W4);
  u16*  W5B  = (u16*)(wsb + OFF_W5);
  float* WL1T = (float*)(wsb + OFF_WL1T);
  float* WL2T = (float*)(wsb + OFF_WL2T);
  float* WL3T = (float*)(wsb + OFF_WL3T);

  SArgs sa; int st = 0;
  auto sset = [&](int i, const float* w, const float* g, u16* dst, int O, int C, int cpl2) {
    sa.seg[i].w = w; sa.seg[i].g = g; sa.seg[i].dst = dst; sa.seg[i].C = C;
    sa.seg[i].cpl2 = cpl2; sa.seg[i].start = st; st += O << cpl2;
  };
  sset(0, m1_w0, m1_g0, M1W0, 64, 6, 5);
  sset(1, m1_wm, m1_gm, M1WM, 64, 64, 6);
  sset(2, m2_w0, m2_g0, M2W0, 64, 128, 7);
  sset(3, m2_wm, m2_gm, M2WM, 64, 64, 6);
  sset(4, w3, g3, W3B, 128, 128, 7);
  sset(5, w4, g4, W4B, 256, 256, 8);
  sset(6, w5, g5, W5B, 1024, 512, 9);
  sa.total = st;

  TArgs3 ta; int tt = 0;
  auto tset = [&](int i, const float* w, const float* g, float* dst, int O, int C) {
    ta.seg[i].w = w; ta.seg[i].g = g; ta.seg[i].dst = dst; ta.seg[i].O = O; ta.seg[i].C = C;
    ta.seg[i].start = tt; tt += O * C;
  };
  tset(0, wl1, bn4_g, WL1T, 512, 2048);
  tset(1, wl2, bn5_g, WL2T, 256, 512);
  tset(2, wl3, nullptr, WL3T, 49, 256);
  ta.total = tt;

  hipLaunchKernelGGL(prep_scale_bf16, dim3((sa.total + 255) / 256), dim3(256), 0, stream, sa);
  hipLaunchKernelGGL(prep_w1s_bf16, dim3(104), dim3(256), 0, stream, m1_w1, m1_ws, m1_go, m1_gs, M1W1S);
  hipLaunchKernelGGL(prep_w1s_bf16, dim3(104), dim3(256), 0, stream, m2_w1, m2_ws, m2_go, m2_gs, M2W1S);
  hipLaunchKernelGGL(prep_transpose_f32, dim3((ta.total + 255) / 256), dim3(256), 0, stream, ta);

  hipLaunchKernelGGL(knn_kernel, dim3(2048), dim3(256), 0, stream, x, IDX);

  hipLaunchKernelGGL((mak_mfma<6>), dim3(256, 1, BB), dim3(256), 0, stream,
                     x, IDX, (const u16*)nullptr, M1W0, m1_b0, M1WM, m1_bm, M1W1S, m1_bo, m1_bs, X1P);
  hipLaunchKernelGGL((mak_mfma<128>), dim3(256, 1, BB), dim3(256), 0, stream,
                     x, IDX, X1P, M2W0, m2_b0, M2WM, m2_bm, M2W1S, m2_bo, m2_bs, X2P);

  hipLaunchKernelGGL((conv_maxk_mfma<128, 128>), dim3(256, 1, BB), dim3(256), 0, stream,
                     X2P, IDX, W3B, b3, X3P);
  hipLaunchKernelGGL((conv_maxk_mfma<256, 256>), dim3(256, 1, BB), dim3(256), 0, stream,
                     X3P, IDX, W4B, b4, X4P);

  hipLaunchKernelGGL(conv5_mfma, dim3(16, 4, BB), dim3(256), 0, stream,
                     X1P, X2P, X3P, X4P, W5B, b5, PMAX, PSUM);
  hipLaunchKernelGGL(reduce5, dim3(32), dim3(256), 0, stream, PMAX, PSUM, XPg);

  hipLaunchKernelGGL(fc1_kernel, dim3(8, BB), dim3(256), 0, stream, XPg, WL1T, bn4_b, XF1);
  hipLaunchKernelGGL(fc2_kernel, dim3(4, BB), dim3(256), 0, stream, XF1, WL2T, bl2, bn5_g, bn5_b, XF2);
  hipLaunchKernelGGL(fc3_kernel, dim3(1, BB), dim3(256), 0, stream, XF2, WL3T, bl3, (float*)d_out);
}

// Round 4
// 451.399 us; speedup vs baseline: 2.3715x; 1.0743x over previous
//
#include <hip/hip_runtime.h>
#include <math.h>

#define BB 8
#define NN 1024
#define KK 16
#define NKP (NN*KK)
#define BN_INV 0.99999500003749981f

typedef unsigned short u16;
typedef __attribute__((ext_vector_type(8))) short short8;
typedef __attribute__((ext_vector_type(4))) float f32x4;

#define MFMA16(a,b,c) __builtin_amdgcn_mfma_f32_16x16x32_bf16(a,b,c,0,0,0)

__device__ __forceinline__ float lrelu(float v) { return v >= 0.f ? v : 0.2f * v; }

__device__ __forceinline__ u16 f2bf(float f) {
  union { float f; unsigned u; } v; v.f = f;
  unsigned r = v.u + 0x7fff + ((v.u >> 16) & 1);
  return (u16)(r >> 16);
}
__device__ __forceinline__ float bf2f(u16 s) {
  union { unsigned u; float f; } v; v.u = ((unsigned)s) << 16;
  return v.f;
}

// ---------------- workspace byte offsets ----------------
constexpr size_t OFF_IDX   = 0;          // int[8*1024*16]
constexpr size_t OFF_X1P   = 524288;     // bf16 [8][1024][64]
constexpr size_t OFF_X2P   = 1572864;
constexpr size_t OFF_X3P   = 2621440;    // bf16 [8][1024][128]
constexpr size_t OFF_X4P   = 4718592;    // bf16 [8][1024][256]
constexpr size_t OFF_PMAX  = 8912896;    // f32 [8][16][1024]
constexpr size_t OFF_PSUM  = 9437184;
constexpr size_t OFF_XP    = 9961472;    // f32 [8][2048]
constexpr size_t OFF_XF1   = 10027008;   // f32 [8][512]
constexpr size_t OFF_XF2   = 10043392;   // f32 [8][256]
constexpr size_t OFF_M1W0  = 10051584;   // bf16 [1][64][32] chunk-major (6 real c)
constexpr size_t OFF_M1WM  = 10055680;   // bf16 [2][64][32]
constexpr size_t OFF_M1W1S = 10063872;   // bf16 [13][64][32]
constexpr size_t OFF_M2W0  = 10117120;   // bf16 [4][64][32]
constexpr size_t OFF_M2WM  = 10133504;   // bf16 [2][64][32]
constexpr size_t OFF_M2W1S = 10141696;   // bf16 [13][64][32]
constexpr size_t OFF_W3    = 10194944;   // bf16 [4][128][32]
constexpr size_t OFF_W4    = 10227712;   // bf16 [8][256][32]
constexpr size_t OFF_W5    = 10358784;   // bf16 [16][1024][32]
constexpr size_t OFF_WL1T  = 11407360;   // f32 [2048][512]
constexpr size_t OFF_WL2T  = 15601664;   // f32 [512][256]
constexpr size_t OFF_WL3T  = 16125952;   // f32 [256][49]

// ---------------- weight prep: chunk-major bf16 [Cp/32][O][32] with gamma fold ----------------
struct SSeg { const float* w; const float* g; u16* dst; int O; int C; int cpl2; int start; };
struct SArgs { SSeg seg[7]; int total; };

__global__ __launch_bounds__(256) void prep_scale_bf16(SArgs a) {
  const int tid = blockIdx.x * 256 + threadIdx.x;
  if (tid >= a.total) return;
  int s = 0;
  #pragma unroll
  for (int i = 1; i < 7; ++i) if (tid >= a.seg[i].start) s = i;
  const SSeg sg = a.seg[s];
  const int e = tid - sg.start;
  const int o = e >> sg.cpl2;
  const int c = e & ((1 << sg.cpl2) - 1);
  float v = 0.f;
  if (c < sg.C) v = sg.w[o * sg.C + c] * sg.g[o] * BN_INV;
  sg.dst[(size_t)(c >> 5) * (sg.O * 32) + o * 32 + (c & 31)] = f2bf(v);
}

// w1s virtual-channel weights, chunk-major [13][64][32]
__global__ __launch_bounds__(256) void prep_w1s_bf16(
    const float* __restrict__ w1a, const float* __restrict__ wsa,
    const float* __restrict__ goa, const float* __restrict__ gsa,
    const float* __restrict__ w1b, const float* __restrict__ wsb,
    const float* __restrict__ gob, const float* __restrict__ gsb,
    u16* __restrict__ dsta, u16* __restrict__ dstb) {
  const int tid = blockIdx.x * 256 + threadIdx.x;
  if (tid >= 64 * 416) return;
  const float* w1 = blockIdx.y ? w1b : w1a;
  const float* wsm = blockIdx.y ? wsb : wsa;
  const float* go = blockIdx.y ? gob : goa;
  const float* gs = blockIdx.y ? gsb : gsa;
  u16* dst = blockIdx.y ? dstb : dsta;
  const int o = tid / 416, ci = tid - o * 416;
  float v = 0.f;
  if (ci < 384) {
    const int ii = ci >> 6, ch = ci & 63;
    const int base = (o * 24 + ii * 4) * 64 + ch;
    v = go[o] * BN_INV * (w1[base] + w1[base + 64] + w1[base + 128] + w1[base + 192]);
  } else if (ci < 390) {
    v = gs[o] * BN_INV * wsm[o * 6 + (ci - 384)];
  }
  dst[(size_t)(ci >> 5) * 2048 + o * 32 + (ci & 31)] = f2bf(v);
}

struct TSeg { const float* w; const float* g; float* dst; int O; int C; int start; };
struct TArgs3 { TSeg seg[3]; int total; };

__global__ __launch_bounds__(256) void prep_transpose_f32(TArgs3 a) {
  const int tid = blockIdx.x * 256 + threadIdx.x;
  if (tid >= a.total) return;
  int s = 0;
  #pragma unroll
  for (int i = 1; i < 3; ++i) if (tid >= a.seg[i].start) s = i;
  const TSeg sg = a.seg[s];
  const int e = tid - sg.start;
  const int c = e / sg.O;
  const int o = e - c * sg.O;
  float v = sg.w[o * sg.C + c];
  if (sg.g) v *= sg.g[o] * BN_INV;
  sg.dst[e] = v;
}

// ---------------- KNN (exact fp32) ----------------
__global__ __launch_bounds__(256) void knn_kernel(const float* __restrict__ x, int* __restrict__ idxout) {
  const int wid  = (blockIdx.x * blockDim.x + threadIdx.x) >> 6;
  const int lane = threadIdx.x & 63;
  const int b = wid >> 10;
  const int n = wid & (NN - 1);
  const float* xb = x + b * 3 * NN;
  const float x0n = xb[n], x1n = xb[NN + n], x2n = xb[2 * NN + n];
  const float xxn = x0n * x0n + x1n * x1n + x2n * x2n;
  float pd[16];
  #pragma unroll
  for (int j = 0; j < 16; ++j) {
    const int m = j * 64 + lane;
    const float x0 = xb[m], x1 = xb[NN + m], x2 = xb[2 * NN + m];
    const float dot = x0n * x0 + x1n * x1 + x2n * x2;
    const float xxm = x0 * x0 + x1 * x1 + x2 * x2;
    pd[j] = 2.f * dot - xxn - xxm;
  }
  for (int r = 0; r < 16; ++r) {
    float bv = pd[0]; int bj = 0;
    #pragma unroll
    for (int j = 1; j < 16; ++j) if (pd[j] > bv) { bv = pd[j]; bj = j; }
    int bm = bj * 64 + lane;
    #pragma unroll
    for (int off = 32; off > 0; off >>= 1) {
      const float ov = __shfl_down(bv, off);
      const int   om = __shfl_down(bm, off);
      if (ov > bv || (ov == bv && om < bm)) { bv = ov; bm = om; }
    }
    bm = __shfl(bm, 0);
    if (lane == 0) idxout[wid * KK + r] = bm;
    const int  cj   = bm >> 6;
    const bool mine = (bm & 63) == lane;
    #pragma unroll
    for (int j = 0; j < 16; ++j) if (mine && j == cj) pd[j] = -INFINITY;
  }
}

// ---------------- helpers ----------------
__device__ __forceinline__ short8 diff8s(uint4 qa, uint4 qb) {
  union { uint4 q; short8 v; u16 s[8]; } ua, ub, r;
  ua.q = qa; ub.q = qb;
  #pragma unroll
  for (int j = 0; j < 8; ++j) r.s[j] = f2bf(bf2f(ua.s[j]) - bf2f(ub.s[j]));
  return r.v;
}

// swizzled [64p][64c] LDS tile: group g of row p at pos = g ^ (p&7)
__device__ __forceinline__ short8 bfrag64(const u16* T, int pl, int quad, int c0) {
  const int pos = ((c0 >> 3) + quad) ^ (pl & 7);
  return *(const short8*)(T + pl * 64 + pos * 8);
}
__device__ __forceinline__ void writeD64(u16* T, int pl, int quad, const f32x4 a,
                                         const float* __restrict__ bias, int obase) {
  union { ushort4 v; u16 s[4]; } pk;
  #pragma unroll
  for (int r = 0; r < 4; ++r) pk.s[r] = f2bf(lrelu(a[r] + bias[obase + quad * 4 + r]));
  const int g = (obase + quad * 4) >> 3;
  const int pos = g ^ (pl & 7);
  *(ushort4*)(T + pl * 64 + pos * 8 + (quad & 1) * 4) = pk.v;
}

// ---------------- fused mak block: direct-fragment loads, 3 barriers total ----------------
// CIN_Y = 6 (m1: y = geo, in regs) or 128 (m2: gather from srcp, CH=64)
template<int CIN_Y>
__global__ __launch_bounds__(256) void mak_mfma(
    const float* __restrict__ x, const int* __restrict__ idxb, const u16* __restrict__ srcp,
    const u16* __restrict__ w0b, const float* __restrict__ b0v,
    const u16* __restrict__ wmb, const float* __restrict__ bmv,
    const u16* __restrict__ w1s, const float* __restrict__ bov, const float* __restrict__ bsv,
    u16* __restrict__ Xoutp) {
  __shared__ __align__(16) u16 Y0s[64 * 64];
  __shared__ __align__(16) u16 YMs[64 * 64];
  __shared__ int nbrs[64];

  const int t = threadIdx.x;
  const int b = blockIdx.z;
  const int p0 = blockIdx.x * 64;
  const int w = t >> 6, l = t & 63;
  const int quad = l >> 4, l15 = l & 15;
  const int pl = w * 16 + l15;
  const int cq8 = quad * 8;
  const int nvtx = blockIdx.x * 4 + w;   // center point of this wave's k-group

  if (t < 64) nbrs[t] = idxb[b * NKP + p0 + t] & (NN - 1);
  __syncthreads();
  const int nbr = nbrs[pl];

  // geo channels of point pl, bf16-rounded, in registers
  const float* xb = x + b * 3 * NN;
  u16 geb[6];
  #pragma unroll
  for (int i = 0; i < 3; ++i) {
    geb[i]     = f2bf(xb[i * NN + nbr] - xb[i * NN + nvtx]);
    geb[3 + i] = f2bf(xb[i * NN + nvtx]);
  }
  union { short8 v; u16 s[8]; } bg;
  bg.v = (short8)(short)0;
  if (quad == 0) {
    #pragma unroll
    for (int j = 0; j < 6; ++j) bg.s[j] = geb[j];
  }

  f32x4 acc[4];
  #pragma unroll
  for (int i = 0; i < 4; ++i) acc[i] = (f32x4)0.f;

  // ---- GEMM1: y -> 64 (direct fragment loads) ----
  if constexpr (CIN_Y == 6) {
    #pragma unroll
    for (int at = 0; at < 4; ++at) {
      const short8 af = *(const short8*)(w0b + (size_t)(at * 16 + l15) * 32 + cq8);
      acc[at] = MFMA16(af, bg.v, acc[at]);
    }
  } else {
    constexpr int CH = CIN_Y / 2;
    #pragma unroll
    for (int k = 0; k < CIN_Y / 32; ++k) {
      short8 bf;
      if (k * 32 < CH) {
        const int c = k * 32 + cq8;
        bf = diff8s(*(const uint4*)(srcp + ((size_t)(b * NN + nbr) * CH + c)),
                    *(const uint4*)(srcp + ((size_t)(b * NN + nvtx) * CH + c)));
      } else {
        const int c = k * 32 + cq8 - CH;
        bf = *(const short8*)(srcp + ((size_t)(b * NN + nvtx) * CH + c));
      }
      #pragma unroll
      for (int at = 0; at < 4; ++at) {
        const short8 af = *(const short8*)(w0b + (size_t)(k * 64 + at * 16 + l15) * 32 + cq8);
        acc[at] = MFMA16(af, bf, acc[at]);
      }
    }
  }
  #pragma unroll
  for (int at = 0; at < 4; ++at) writeD64(Y0s, pl, quad, acc[at], b0v, at * 16);
  __syncthreads();

  // ---- GEMM2: 64 -> 64 ----
  #pragma unroll
  for (int i = 0; i < 4; ++i) acc[i] = (f32x4)0.f;
  #pragma unroll
  for (int kc = 0; kc < 2; ++kc) {
    const short8 bf = bfrag64(Y0s, pl, quad, kc * 32);
    #pragma unroll
    for (int at = 0; at < 4; ++at) {
      const short8 af = *(const short8*)(wmb + (size_t)(kc * 64 + at * 16 + l15) * 32 + cq8);
      acc[at] = MFMA16(af, bf, acc[at]);
    }
  }
  #pragma unroll
  for (int at = 0; at < 4; ++at) writeD64(YMs, pl, quad, acc[at], bmv, at * 16);
  __syncthreads();

  // ---- GEMM3: 384 virtual channels (B-frag built in regs) + idt ----
  #pragma unroll
  for (int i = 0; i < 4; ++i) acc[i] = (f32x4)0.f;
  #pragma unroll
  for (int k = 0; k < 12; ++k) {
    const int ii = k >> 1, ch0 = (k & 1) * 32;
    union { short8 v; u16 s[8]; } ym, bfv;
    ym.v = bfrag64(YMs, pl, quad, ch0);
    const float ge = bf2f(geb[ii]);
    #pragma unroll
    for (int j = 0; j < 8; ++j) bfv.s[j] = f2bf(bf2f(ym.s[j]) * ge);
    #pragma unroll
    for (int at = 0; at < 4; ++at) {
      const short8 af = *(const short8*)(w1s + (size_t)(k * 64 + at * 16 + l15) * 32 + cq8);
      acc[at] = MFMA16(af, bfv.v, acc[at]);
    }
  }
  #pragma unroll
  for (int at = 0; at < 4; ++at) {   // idt chunk (k=12): B = geo fragment
    const short8 af = *(const short8*)(w1s + (size_t)(12 * 64 + at * 16 + l15) * 32 + cq8);
    acc[at] = MFMA16(af, bg.v, acc[at]);
  }

  // ---- epilogue: bias + lrelu, max over k=l15 ----
  u16* orow = Xoutp + (size_t)(b * NN + nvtx) * 64;
  #pragma unroll
  for (int at = 0; at < 4; ++at) {
    union { ushort4 v; u16 s[4]; } pk;
    #pragma unroll
    for (int r = 0; r < 4; ++r) {
      const int o = at * 16 + quad * 4 + r;
      float v = lrelu(acc[at][r] + bov[o] + bsv[o]);
      v = fmaxf(v, __shfl_xor(v, 1));
      v = fmaxf(v, __shfl_xor(v, 2));
      v = fmaxf(v, __shfl_xor(v, 4));
      v = fmaxf(v, __shfl_xor(v, 8));
      pk.s[r] = f2bf(v);
    }
    if (l15 == 0) *(ushort4*)(orow + at * 16 + quad * 4) = pk.v;
  }
}

// ---------------- edge conv: barrier-free direct-fragment MFMA ----------------
template<int CIN, int COUT>
__global__ __launch_bounds__(256) void conv_maxk_mfma(
    const u16* __restrict__ srcp, const int* __restrict__ idxb,
    const u16* __restrict__ wb, const float* __restrict__ bias,
    u16* __restrict__ Xoutp) {
  __shared__ int nbrs[64];
  constexpr int CH = CIN / 2;
  constexpr int OPW = COUT / 4;
  constexpr int NAT = OPW / 16;

  const int t = threadIdx.x;
  const int b = blockIdx.z;
  const int p0 = blockIdx.x * 64;
  const int w = t >> 6, l = t & 63;
  const int quad = l >> 4, l15 = l & 15;
  const int cq8 = quad * 8;
  const int ow0 = w * OPW;

  if (t < 64) nbrs[t] = idxb[b * NKP + p0 + t] & (NN - 1);
  __syncthreads();

  int nbr[4], ctr[4];
  #pragma unroll
  for (int pg = 0; pg < 4; ++pg) {
    nbr[pg] = nbrs[pg * 16 + l15];
    ctr[pg] = blockIdx.x * 4 + pg;
  }

  f32x4 acc[NAT][4];
  #pragma unroll
  for (int i = 0; i < NAT; ++i)
    #pragma unroll
    for (int j = 0; j < 4; ++j) acc[i][j] = (f32x4)0.f;

  #pragma unroll 4
  for (int k = 0; k < CIN / 32; ++k) {
    short8 bfr[4];
    if (k * 32 < CH) {
      const int c = k * 32 + cq8;
      #pragma unroll
      for (int pg = 0; pg < 4; ++pg)
        bfr[pg] = diff8s(*(const uint4*)(srcp + ((size_t)(b * NN + nbr[pg]) * CH + c)),
                         *(const uint4*)(srcp + ((size_t)(b * NN + ctr[pg]) * CH + c)));
    } else {
      const int c = k * 32 + cq8 - CH;
      #pragma unroll
      for (int pg = 0; pg < 4; ++pg)
        bfr[pg] = *(const short8*)(srcp + ((size_t)(b * NN + ctr[pg]) * CH + c));
    }
    #pragma unroll
    for (int at = 0; at < NAT; ++at) {
      const short8 af = *(const short8*)(wb + ((size_t)(k * COUT + ow0 + at * 16 + l15)) * 32 + cq8);
      #pragma unroll
      for (int pg = 0; pg < 4; ++pg) acc[at][pg] = MFMA16(af, bfr[pg], acc[at][pg]);
    }
  }

  #pragma unroll
  for (int pg = 0; pg < 4; ++pg) {
    u16* orow = Xoutp + (size_t)(b * NN + ctr[pg]) * COUT + ow0;
    #pragma unroll
    for (int at = 0; at < NAT; ++at) {
      union { ushort4 v; u16 s[4]; } pk;
      #pragma unroll
      for (int r = 0; r < 4; ++r) {
        float v = lrelu(acc[at][pg][r] + bias[ow0 + at * 16 + quad * 4 + r]);
        v = fmaxf(v, __shfl_xor(v, 1));
        v = fmaxf(v, __shfl_xor(v, 2));
        v = fmaxf(v, __shfl_xor(v, 4));
        v = fmaxf(v, __shfl_xor(v, 8));
        pk.s[r] = f2bf(v);
      }
      if (l15 == 0) *(ushort4*)(orow + at * 16 + quad * 4) = pk.v;
    }
  }
}

// ---------------- conv5: barrier-free direct-fragment MFMA, partial max/sum ----------------
__global__ __launch_bounds__(256) void conv5_mfma(
    const u16* __restrict__ X1P, const u16* __restrict__ X2P,
    const u16* __restrict__ X3P, const u16* __restrict__ X4P,
    const u16* __restrict__ w5b, const float* __restrict__ b5,
    float* __restrict__ PMAX, float* __restrict__ PSUM) {
  const int t = threadIdx.x;
  const int b = blockIdx.z;
  const int n0 = blockIdx.x * 64;
  const int w = t >> 6, l = t & 63;
  const int quad = l >> 4, l15 = l & 15;
  const int cq8 = quad * 8;
  const int ow0 = blockIdx.y * 256 + w * 64;

  f32x4 acc[4][4];
  #pragma unroll
  for (int i = 0; i < 4; ++i)
    #pragma unroll
    for (int j = 0; j < 4; ++j) acc[i][j] = (f32x4)0.f;

  #pragma unroll 4
  for (int k = 0; k < 16; ++k) {
    const int c = k * 32 + cq8;
    short8 bfr[4];
    #pragma unroll
    for (int pg = 0; pg < 4; ++pg) {
      const int n = n0 + pg * 16 + l15;
      const u16* src; int cc;
      if (c < 64)       { src = X1P + (size_t)(b * NN + n) * 64;  cc = c; }
      else if (c < 128) { src = X2P + (size_t)(b * NN + n) * 64;  cc = c - 64; }
      else if (c < 256) { src = X3P + (size_t)(b * NN + n) * 128; cc = c - 128; }
      else              { src = X4P + (size_t)(b * NN + n) * 256; cc = c - 256; }
      bfr[pg] = *(const short8*)(src + cc);
    }
    #pragma unroll
    for (int at = 0; at < 4; ++at) {
      const short8 af = *(const short8*)(w5b + ((size_t)(k * 1024 + ow0 + at * 16 + l15)) * 32 + cq8);
      #pragma unroll
      for (int pg = 0; pg < 4; ++pg) acc[at][pg] = MFMA16(af, bfr[pg], acc[at][pg]);
    }
  }

  #pragma unroll
  for (int at = 0; at < 4; ++at) {
    f32x4 pmx, psm;
    #pragma unroll
    for (int r = 0; r < 4; ++r) {
      const float bb = b5[ow0 + at * 16 + quad * 4 + r];
      float m = -INFINITY, s = 0.f;
      #pragma unroll
      for (int pg = 0; pg < 4; ++pg) {
        const float v = lrelu(acc[at][pg][r] + bb);
        m = fmaxf(m, v); s += v;
      }
      #pragma unroll
      for (int msk = 1; msk < 16; msk <<= 1) {
        m = fmaxf(m, __shfl_xor(m, msk));
        s += __shfl_xor(s, msk);
      }
      pmx[r] = m; psm[r] = s;
    }
    if (l15 == 0) {
      float* dm = PMAX + (size_t)(b * 16 + blockIdx.x) * 1024 + ow0 + at * 16 + quad * 4;
      float* ds = PSUM + (size_t)(b * 16 + blockIdx.x) * 1024 + ow0 + at * 16 + quad * 4;
      *(f32x4*)dm = pmx;
      *(f32x4*)ds = psm;
    }
  }
}

__global__ __launch_bounds__(256) void reduce5(const float* __restrict__ PMAX, const float* __restrict__ PSUM,
                                               float* __restrict__ XPg) {
  const int tid = blockIdx.x * 256 + threadIdx.x;  // 8192
  const int b = tid >> 10, o = tid & 1023;
  float m = -INFINITY, s = 0.f;
  for (int pt = 0; pt < 16; ++pt) {
    m = fmaxf(m, PMAX[(size_t)(b * 16 + pt) * 1024 + o]);
    s += PSUM[(size_t)(b * 16 + pt) * 1024 + o];
  }
  XPg[b * 2048 + o] = m;
  XPg[b * 2048 + 1024 + o] = s * (1.f / 1024.f);
}

// ---------------- FC head ----------------
__global__ __launch_bounds__(256) void fc1_kernel(const float* __restrict__ XPg, const float* __restrict__ wl1t,
                                                  const float* __restrict__ bn4_b, float* __restrict__ XF1) {
  __shared__ float red[64 * 5];
  const int t = threadIdx.x;
  const int b = blockIdx.y;
  const int o = blockIdx.x * 64 + (t & 63);
  const int cq = t >> 6;
  const float* xp = XPg + b * 2048;
  float acc = 0.f;
  for (int c = cq * 512; c < cq * 512 + 512; ++c) acc = fmaf(wl1t[c * 512 + o], xp[c], acc);
  red[(t & 63) * 5 + cq] = acc;
  __syncthreads();
  if (t < 64) {
    const int oo = blockIdx.x * 64 + t;
    const float v = red[t * 5] + red[t * 5 + 1] + red[t * 5 + 2] + red[t * 5 + 3] + bn4_b[oo];
    XF1[b * 512 + oo] = lrelu(v);
  }
}

__global__ __launch_bounds__(256) void fc2_kernel(const float* __restrict__ XF1, const float* __restrict__ wl2t,
                                                  const float* __restrict__ bl2, const float* __restrict__ bn5_g,
                                                  const float* __restrict__ bn5_b, float* __restrict__ XF2) {
  __shared__ float red[64 * 5];
  const int t = threadIdx.x;
  const int b = blockIdx.y;
  const int o = blockIdx.x * 64 + (t & 63);
  const int cq = t >> 6;
  const float* xf = XF1 + b * 512;
  float acc = 0.f;
  for (int c = cq * 128; c < cq * 128 + 128; ++c) acc = fmaf(wl2t[c * 256 + o], xf[c], acc);
  red[(t & 63) * 5 + cq] = acc;
  __syncthreads();
  if (t < 64) {
    const int oo = blockIdx.x * 64 + t;
    const float bias = bl2[oo] * (bn5_g[oo] * BN_INV) + bn5_b[oo];
    const float v = red[t * 5] + red[t * 5 + 1] + red[t * 5 + 2] + red[t * 5 + 3] + bias;
    XF2[b * 256 + oo] = lrelu(v);
  }
}

__global__ __launch_bounds__(256) void fc3_kernel(const float* __restrict__ XF2, const float* __restrict__ wl3t,
                                                  const float* __restrict__ bl3, float* __restrict__ out) {
  __shared__ float red[64 * 5];
  const int t = threadIdx.x;
  const int b = blockIdx.y;
  const int ol = t & 63;
  const int cq = t >> 6;
  const float* xf = XF2 + b * 256;
  float acc = 0.f;
  if (ol < 49) for (int c = cq * 64; c < cq * 64 + 64; ++c) acc = fmaf(wl3t[c * 49 + ol], xf[c], acc);
  red[ol * 5 + cq] = acc;
  __syncthreads();
  if (t < 49) out[b * 49 + t] = red[t * 5] + red[t * 5 + 1] + red[t * 5 + 2] + red[t * 5 + 3] + bl3[t];
}

// ---------------- host ----------------
extern "C" void kernel_launch(void* const* d_in, const int* in_sizes, int n_in,
                              void* d_out, int out_size, void* d_ws, size_t ws_size,
                              hipStream_t stream) {
  (void)in_sizes; (void)n_in; (void)out_size; (void)ws_size;
  const float* x     = (const float*)d_in[0];
  const float* m1_w0 = (const float*)d_in[1];
  const float* m1_g0 = (const float*)d_in[2];
  const float* m1_b0 = (const float*)d_in[3];
  const float* m1_wm = (const float*)d_in[4];
  const float* m1_gm = (const float*)d_in[5];
  const float* m1_bm = (const float*)d_in[6];
  const float* m1_w1 = (const float*)d_in[7];
  const float* m1_go = (const float*)d_in[8];
  const float* m1_bo = (const float*)d_in[9];
  const float* m1_ws = (const float*)d_in[10];
  const float* m1_gs = (const float*)d_in[11];
  const float* m1_bs = (const float*)d_in[12];
  const float* m2_w0 = (const float*)d_in[13];
  const float* m2_g0 = (const float*)d_in[14];
  const float* m2_b0 = (const float*)d_in[15];
  const float* m2_wm = (const float*)d_in[16];
  const float* m2_gm = (const float*)d_in[17];
  const float* m2_bm = (const float*)d_in[18];
  const float* m2_w1 = (const float*)d_in[19];
  const float* m2_go = (const float*)d_in[20];
  const float* m2_bo = (const float*)d_in[21];
  const float* m2_ws = (const float*)d_in[22];
  const float* m2_gs = (const float*)d_in[23];
  const float* m2_bs = (const float*)d_in[24];
  const float* w3    = (const float*)d_in[25];
  const float* g3    = (const float*)d_in[26];
  const float* b3    = (const float*)d_in[27];
  const float* w4    = (const float*)d_in[28];
  const float* g4    = (const float*)d_in[29];
  const float* b4    = (const float*)d_in[30];
  const float* w5    = (const float*)d_in[31];
  const float* g5    = (const float*)d_in[32];
  const float* b5    = (const float*)d_in[33];
  const float* wl1   = (const float*)d_in[34];
  const float* bn4_g = (const float*)d_in[35];
  const float* bn4_b = (const float*)d_in[36];
  const float* wl2   = (const float*)d_in[37];
  const float* bl2   = (const float*)d_in[38];
  const float* bn5_g = (const float*)d_in[39];
  const float* bn5_b = (const float*)d_in[40];
  const float* wl3   = (const float*)d_in[41];
  const float* bl3   = (const float*)d_in[42];

  char* wsb = (char*)d_ws;
  int*  IDX  = (int*)(wsb + OFF_IDX);
  u16*  X1P  = (u16*)(wsb + OFF_X1P);
  u16*  X2P  = (u16*)(wsb + OFF_X2P);
  u16*  X3P  = (u16*)(wsb + OFF_X3P);
  u16*  X4P  = (u16*)(wsb + OFF_X4P);
  float* PMAX = (float*)(wsb + OFF_PMAX);
  float* PSUM = (float*)(wsb + OFF_PSUM);
  float* XPg  = (float*)(wsb + OFF_XP);
  float* XF1  = (float*)(wsb + OFF_XF1);
  float* XF2  = (float*)(wsb + OFF_XF2);
  u16*  M1W0 = (u16*)(wsb + OFF_M1W0);
  u16*  M1WM = (u16*)(wsb + OFF_M1WM);
  u16*  M1W1S = (u16*)(wsb + OFF_M1W1S);
  u16*  M2W0 = (u16*)(wsb + OFF_M2W0);
  u16*  M2WM = (u16*)(wsb + OFF_M2WM);
  u16*  M2W1S = (u16*)(wsb + OFF_M2W1S);
  u16*  W3B  = (u16*)(wsb + OFF_W3);
  u16*  W4B  = (u16*)(wsb + OFF_W4);
  u16*  W5B  = (u16*)(wsb + OFF_W5);
  float* WL1T = (float*)(wsb + OFF_WL1T);
  float* WL2T = (float*)(wsb + OFF_WL2T);
  float* WL3T = (float*)(wsb + OFF_WL3T);

  SArgs sa; int st = 0;
  auto sset = [&](int i, const float* w, const float* g, u16* dst, int O, int C, int cpl2) {
    sa.seg[i].w = w; sa.seg[i].g = g; sa.seg[i].dst = dst; sa.seg[i].O = O; sa.seg[i].C = C;
    sa.seg[i].cpl2 = cpl2; sa.seg[i].start = st; st += O << cpl2;
  };
  sset(0, m1_w0, m1_g0, M1W0, 64, 6, 5);
  sset(1, m1_wm, m1_gm, M1WM, 64, 64, 6);
  sset(2, m2_w0, m2_g0, M2W0, 64, 128, 7);
  sset(3, m2_wm, m2_gm, M2WM, 64, 64, 6);
  sset(4, w3, g3, W3B, 128, 128, 7);
  sset(5, w4, g4, W4B, 256, 256, 8);
  sset(6, w5, g5, W5B, 1024, 512, 9);
  sa.total = st;

  TArgs3 ta; int tt = 0;
  auto tset = [&](int i, const float* w, const float* g, float* dst, int O, int C) {
    ta.seg[i].w = w; ta.seg[i].g = g; ta.seg[i].dst = dst; ta.seg[i].O = O; ta.seg[i].C = C;
    ta.seg[i].start = tt; tt += O * C;
  };
  tset(0, wl1, bn4_g, WL1T, 512, 2048);
  tset(1, wl2, bn5_g, WL2T, 256, 512);
  tset(2, wl3, nullptr, WL3T, 49, 256);
  ta.total = tt;

  hipLaunchKernelGGL(prep_scale_bf16, dim3((sa.total + 255) / 256), dim3(256), 0, stream, sa);
  hipLaunchKernelGGL(prep_w1s_bf16, dim3(104, 2), dim3(256), 0, stream,
                     m1_w1, m1_ws, m1_go, m1_gs, m2_w1, m2_ws, m2_go, m2_gs, M1W1S, M2W1S);
  hipLaunchKernelGGL(prep_transpose_f32, dim3((ta.total + 255) / 256), dim3(256), 0, stream, ta);

  hipLaunchKernelGGL(knn_kernel, dim3(2048), dim3(256), 0, stream, x, IDX);

  hipLaunchKernelGGL((mak_mfma<6>), dim3(256, 1, BB), dim3(256), 0, stream,
                     x, IDX, (const u16*)nullptr, M1W0, m1_b0, M1WM, m1_bm, M1W1S, m1_bo, m1_bs, X1P);
  hipLaunchKernelGGL((mak_mfma<128>), dim3(256, 1, BB), dim3(256), 0, stream,
                     x, IDX, X1P, M2W0, m2_b0, M2WM, m2_bm, M2W1S, m2_bo, m2_bs, X2P);

  hipLaunchKernelGGL((conv_maxk_mfma<128, 128>), dim3(256, 1, BB), dim3(256), 0, stream,
                     X2P, IDX, W3B, b3, X3P);
  hipLaunchKernelGGL((conv_maxk_mfma<256, 256>), dim3(256, 1, BB), dim3(256), 0, stream,
                     X3P, IDX, W4B, b4, X4P);

  hipLaunchKernelGGL(conv5_mfma, dim3(16, 4, BB), dim3(256), 0, stream,
                     X1P, X2P, X3P, X4P, W5B, b5, PMAX, PSUM);
  hipLaunchKernelGGL(reduce5, dim3(32), dim3(256), 0, stream, PMAX, PSUM, XPg);

  hipLaunchKernelGGL(fc1_kernel, dim3(8, BB), dim3(256), 0, stream, XPg, WL1T, bn4_b, XF1);
  hipLaunchKernelGGL(fc2_kernel, dim3(4, BB), dim3(256), 0, stream, XF1, WL2T, bl2, bn5_g, bn5_b, XF2);
  hipLaunchKernelGGL(fc3_kernel, dim3(1, BB), dim3(256), 0, stream, XF2, WL3T, bl3, (float*)d_out);
}

// Round 5
// 435.939 us; speedup vs baseline: 2.4556x; 1.0355x over previous
//
#include <hip/hip_runtime.h>
#include <math.h>

#define BB 8
#define NN 1024
#define KK 16
#define NKP (NN*KK)
#define BN_INV 0.99999500003749981f

typedef unsigned short u16;
typedef __attribute__((ext_vector_type(8))) short short8;
typedef __attribute__((ext_vector_type(4))) float f32x4;

#define MFMA16(a,b,c) __builtin_amdgcn_mfma_f32_16x16x32_bf16(a,b,c,0,0,0)

__device__ __forceinline__ float lrelu(float v) { return v >= 0.f ? v : 0.2f * v; }

__device__ __forceinline__ u16 f2bf(float f) {
  union { float f; unsigned u; } v; v.f = f;
  unsigned r = v.u + 0x7fff + ((v.u >> 16) & 1);
  return (u16)(r >> 16);
}
__device__ __forceinline__ float bf2f(u16 s) {
  union { unsigned u; float f; } v; v.u = ((unsigned)s) << 16;
  return v.f;
}

// ---------------- workspace byte offsets ----------------
constexpr size_t OFF_IDX   = 0;          // int[8*1024*16]
constexpr size_t OFF_X1P   = 524288;     // bf16 [8][1024][64]
constexpr size_t OFF_X2P   = 1572864;
constexpr size_t OFF_X3P   = 2621440;    // bf16 [8][1024][128]
constexpr size_t OFF_X4P   = 4718592;    // bf16 [8][1024][256]
constexpr size_t OFF_PMAX  = 8912896;    // f32 [8][16][1024]
constexpr size_t OFF_PSUM  = 9437184;
constexpr size_t OFF_XP    = 9961472;    // f32 [8][2048]
constexpr size_t OFF_XF1   = 10027008;   // f32 [8][512]
constexpr size_t OFF_XF2   = 10043392;   // f32 [8][256]
constexpr size_t OFF_M1W0  = 10051584;   // bf16 [1][64][32] (plain: B carries diffs)
constexpr size_t OFF_M1WM  = 10055680;   // bf16 [2][64][32]
constexpr size_t OFF_M1W1S = 10063872;   // bf16 [13][64][32]
constexpr size_t OFF_M2W0  = 10117120;   // bf16 [4][64][32] edge-folded [Wd|Wc-Wd]
constexpr size_t OFF_M2WM  = 10133504;   // bf16 [2][64][32]
constexpr size_t OFF_M2W1S = 10141696;   // bf16 [13][64][32]
constexpr size_t OFF_W3    = 10194944;   // bf16 [4][128][32] edge-folded
constexpr size_t OFF_W4    = 10227712;   // bf16 [8][256][32] edge-folded
constexpr size_t OFF_W5    = 10358784;   // bf16 [16][1024][32]
constexpr size_t OFF_WL1T  = 11407360;   // f32 [2048][512]
constexpr size_t OFF_WL2T  = 15601664;   // f32 [512][256]
constexpr size_t OFF_WL3T  = 16125952;   // f32 [256][49]

// ---------------- weight prep: chunk-major bf16 [C/32][O][32], gamma fold, optional edge fold ----------------
struct SSeg { const float* w; const float* g; u16* dst; int O; int C; int cpl2; int ch; int start; };
struct SArgs { SSeg seg[7]; int total; };

__global__ __launch_bounds__(256) void prep_scale_bf16(SArgs a) {
  const int tid = blockIdx.x * 256 + threadIdx.x;
  if (tid >= a.total) return;
  int s = 0;
  #pragma unroll
  for (int i = 1; i < 7; ++i) if (tid >= a.seg[i].start) s = i;
  const SSeg sg = a.seg[s];
  const int e = tid - sg.start;
  const int o = e >> sg.cpl2;
  const int c = e & ((1 << sg.cpl2) - 1);
  float v = 0.f;
  if (c < sg.C) {
    v = sg.w[o * sg.C + c];
    if (sg.ch && c >= sg.ch) v -= sg.w[o * sg.C + c - sg.ch];  // Wc - Wd (edge fold)
    v *= sg.g[o] * BN_INV;
  }
  sg.dst[(size_t)(c >> 5) * (sg.O * 32) + o * 32 + (c & 31)] = f2bf(v);
}

// w1s virtual-channel weights, chunk-major [13][64][32] (plain idt rows; B carries geo diffs)
__global__ __launch_bounds__(256) void prep_w1s_bf16(
    const float* __restrict__ w1a, const float* __restrict__ wsa,
    const float* __restrict__ goa, const float* __restrict__ gsa,
    const float* __restrict__ w1b, const float* __restrict__ wsb,
    const float* __restrict__ gob, const float* __restrict__ gsb,
    u16* __restrict__ dsta, u16* __restrict__ dstb) {
  const int tid = blockIdx.x * 256 + threadIdx.x;
  if (tid >= 64 * 416) return;
  const float* w1 = blockIdx.y ? w1b : w1a;
  const float* wsm = blockIdx.y ? wsb : wsa;
  const float* go = blockIdx.y ? gob : goa;
  const float* gs = blockIdx.y ? gsb : gsa;
  u16* dst = blockIdx.y ? dstb : dsta;
  const int o = tid / 416, ci = tid - o * 416;
  float v = 0.f;
  if (ci < 384) {
    const int ii = ci >> 6, ch = ci & 63;
    const int base = (o * 24 + ii * 4) * 64 + ch;
    v = go[o] * BN_INV * (w1[base] + w1[base + 64] + w1[base + 128] + w1[base + 192]);
  } else if (ci < 390) {
    v = gs[o] * BN_INV * wsm[o * 6 + (ci - 384)];
  }
  dst[(size_t)(ci >> 5) * 2048 + o * 32 + (ci & 31)] = f2bf(v);
}

struct TSeg { const float* w; const float* g; float* dst; int O; int C; int start; };
struct TArgs3 { TSeg seg[3]; int total; };

__global__ __launch_bounds__(256) void prep_transpose_f32(TArgs3 a) {
  const int tid = blockIdx.x * 256 + threadIdx.x;
  if (tid >= a.total) return;
  int s = 0;
  #pragma unroll
  for (int i = 1; i < 3; ++i) if (tid >= a.seg[i].start) s = i;
  const TSeg sg = a.seg[s];
  const int e = tid - sg.start;
  const int c = e / sg.O;
  const int o = e - c * sg.O;
  float v = sg.w[o * sg.C + c];
  if (sg.g) v *= sg.g[o] * BN_INV;
  sg.dst[e] = v;
}

// ---------------- KNN (exact fp32) ----------------
__global__ __launch_bounds__(256) void knn_kernel(const float* __restrict__ x, int* __restrict__ idxout) {
  const int wid  = (blockIdx.x * blockDim.x + threadIdx.x) >> 6;
  const int lane = threadIdx.x & 63;
  const int b = wid >> 10;
  const int n = wid & (NN - 1);
  const float* xb = x + b * 3 * NN;
  const float x0n = xb[n], x1n = xb[NN + n], x2n = xb[2 * NN + n];
  const float xxn = x0n * x0n + x1n * x1n + x2n * x2n;
  float pd[16];
  #pragma unroll
  for (int j = 0; j < 16; ++j) {
    const int m = j * 64 + lane;
    const float x0 = xb[m], x1 = xb[NN + m], x2 = xb[2 * NN + m];
    const float dot = x0n * x0 + x1n * x1 + x2n * x2;
    const float xxm = x0 * x0 + x1 * x1 + x2 * x2;
    pd[j] = 2.f * dot - xxn - xxm;
  }
  for (int r = 0; r < 16; ++r) {
    float bv = pd[0]; int bj = 0;
    #pragma unroll
    for (int j = 1; j < 16; ++j) if (pd[j] > bv) { bv = pd[j]; bj = j; }
    int bm = bj * 64 + lane;
    #pragma unroll
    for (int off = 32; off > 0; off >>= 1) {
      const float ov = __shfl_down(bv, off);
      const int   om = __shfl_down(bm, off);
      if (ov > bv || (ov == bv && om < bm)) { bv = ov; bm = om; }
    }
    bm = __shfl(bm, 0);
    if (lane == 0) idxout[wid * KK + r] = bm;
    const int  cj   = bm >> 6;
    const bool mine = (bm & 63) == lane;
    #pragma unroll
    for (int j = 0; j < 16; ++j) if (mine && j == cj) pd[j] = -INFINITY;
  }
}

// ---------------- helpers ----------------
// swizzled [64p][64c] LDS tile: group g of row p at pos = g ^ (p&7)
__device__ __forceinline__ short8 bfrag64(const u16* T, int pl, int quad, int c0) {
  const int pos = ((c0 >> 3) + quad) ^ (pl & 7);
  return *(const short8*)(T + pl * 64 + pos * 8);
}
__device__ __forceinline__ void writeD64(u16* T, int pl, int quad, const f32x4 a,
                                         const float* __restrict__ bias, int obase) {
  union { ushort4 v; u16 s[4]; } pk;
  #pragma unroll
  for (int r = 0; r < 4; ++r) pk.s[r] = f2bf(lrelu(a[r] + bias[obase + quad * 4 + r]));
  const int g = (obase + quad * 4) >> 3;
  const int pos = g ^ (pl & 7);
  *(ushort4*)(T + pl * 64 + pos * 8 + (quad & 1) * 4) = pk.v;
}

// ---------------- fused mak block ----------------
// CIN_Y = 6 (m1: y = geo in regs, plain w0) or 128 (m2: raw x1p rows, edge-folded w0)
template<int CIN_Y>
__global__ __launch_bounds__(256) void mak_mfma(
    const float* __restrict__ x, const int* __restrict__ idxb, const u16* __restrict__ srcp,
    const u16* __restrict__ w0b, const float* __restrict__ b0v,
    const u16* __restrict__ wmb, const float* __restrict__ bmv,
    const u16* __restrict__ w1s, const float* __restrict__ bov, const float* __restrict__ bsv,
    u16* __restrict__ Xoutp) {
  __shared__ __align__(16) u16 Y0s[64 * 64];
  __shared__ __align__(16) u16 YMs[64 * 64];
  __shared__ int nbrs[64];

  const int t = threadIdx.x;
  const int b = blockIdx.z;
  const int p0 = blockIdx.x * 64;
  const int w = t >> 6, l = t & 63;
  const int quad = l >> 4, l15 = l & 15;
  const int pl = w * 16 + l15;
  const int cq8 = quad * 8;
  const int nvtx = blockIdx.x * 4 + w;   // center point of this wave's k-group

  if (t < 64) nbrs[t] = idxb[b * NKP + p0 + t] & (NN - 1);
  __syncthreads();
  const int nbr = nbrs[pl];

  // geo of point pl: fp32 coords -> fp32 diffs -> bf16 (exact old numerics)
  const float* xb = x + b * 3 * NN;
  float ge[6];
  #pragma unroll
  for (int i = 0; i < 3; ++i) {
    const float fc = xb[i * NN + nvtx];
    ge[i]     = xb[i * NN + nbr] - fc;
    ge[3 + i] = fc;
  }
  union { short8 v; u16 s[8]; } bg;
  bg.v = (short8)(short)0;
  if (quad == 0) {
    #pragma unroll
    for (int j = 0; j < 6; ++j) bg.s[j] = f2bf(ge[j]);
  }

  f32x4 acc[4];
  #pragma unroll
  for (int i = 0; i < 4; ++i) acc[i] = (f32x4)0.f;

  // ---- GEMM1: y -> 64 ----
  if constexpr (CIN_Y == 6) {
    #pragma unroll
    for (int at = 0; at < 4; ++at) {
      const short8 af = *(const short8*)(w0b + (size_t)(at * 16 + l15) * 32 + cq8);
      acc[at] = MFMA16(af, bg.v, acc[at]);
    }
  } else {
    // edge-folded weights: chunks 0-1 = nbr row, 2-3 = ctr row (raw loads)
    #pragma unroll
    for (int k = 0; k < 4; ++k) {
      const u16* row = srcp + (size_t)(b * NN + (k < 2 ? nbr : nvtx)) * 64;
      const short8 bf = *(const short8*)(row + (k & 1) * 32 + cq8);
      #pragma unroll
      for (int at = 0; at < 4; ++at) {
        const short8 af = *(const short8*)(w0b + (size_t)(k * 64 + at * 16 + l15) * 32 + cq8);
        acc[at] = MFMA16(af, bf, acc[at]);
      }
    }
  }
  #pragma unroll
  for (int at = 0; at < 4; ++at) writeD64(Y0s, pl, quad, acc[at], b0v, at * 16);
  __syncthreads();

  // ---- GEMM2: 64 -> 64 ----
  #pragma unroll
  for (int i = 0; i < 4; ++i) acc[i] = (f32x4)0.f;
  #pragma unroll
  for (int kc = 0; kc < 2; ++kc) {
    const short8 bf = bfrag64(Y0s, pl, quad, kc * 32);
    #pragma unroll
    for (int at = 0; at < 4; ++at) {
      const short8 af = *(const short8*)(wmb + (size_t)(kc * 64 + at * 16 + l15) * 32 + cq8);
      acc[at] = MFMA16(af, bf, acc[at]);
    }
  }
  #pragma unroll
  for (int at = 0; at < 4; ++at) writeD64(YMs, pl, quad, acc[at], bmv, at * 16);
  __syncthreads();

  // ---- GEMM3: 6 partial K=64 GEMMs, fp32 per-point multiplier post-MFMA ----
  #pragma unroll
  for (int i = 0; i < 4; ++i) acc[i] = (f32x4)0.f;
  #pragma unroll
  for (int ii = 0; ii < 6; ++ii) {
    f32x4 tacc[4];
    #pragma unroll
    for (int i = 0; i < 4; ++i) tacc[i] = (f32x4)0.f;
    #pragma unroll
    for (int kc = 0; kc < 2; ++kc) {
      const short8 bf = bfrag64(YMs, pl, quad, kc * 32);
      #pragma unroll
      for (int at = 0; at < 4; ++at) {
        const short8 af = *(const short8*)(w1s + (size_t)((ii * 2 + kc) * 64 + at * 16 + l15) * 32 + cq8);
        tacc[at] = MFMA16(af, bf, tacc[at]);
      }
    }
    const float g = ge[ii];
    #pragma unroll
    for (int at = 0; at < 4; ++at) acc[at] += g * tacc[at];
  }
  #pragma unroll
  for (int at = 0; at < 4; ++at) {   // idt chunk (k=12): B = geo fragment
    const short8 af = *(const short8*)(w1s + (size_t)(12 * 64 + at * 16 + l15) * 32 + cq8);
    acc[at] = MFMA16(af, bg.v, acc[at]);
  }

  // ---- epilogue: bias + lrelu, max over k=l15 ----
  u16* orow = Xoutp + (size_t)(b * NN + nvtx) * 64;
  #pragma unroll
  for (int at = 0; at < 4; ++at) {
    union { ushort4 v; u16 s[4]; } pk;
    #pragma unroll
    for (int r = 0; r < 4; ++r) {
      const int o = at * 16 + quad * 4 + r;
      float v = lrelu(acc[at][r] + bov[o] + bsv[o]);
      v = fmaxf(v, __shfl_xor(v, 1));
      v = fmaxf(v, __shfl_xor(v, 2));
      v = fmaxf(v, __shfl_xor(v, 4));
      v = fmaxf(v, __shfl_xor(v, 8));
      pk.s[r] = f2bf(v);
    }
    if (l15 == 0) *(ushort4*)(orow + at * 16 + quad * 4) = pk.v;
  }
}

// ---------------- edge conv: raw-load direct-fragment MFMA (edge-folded weights) ----------------
template<int CIN, int COUT>
__global__ __launch_bounds__(256) void conv_maxk_mfma(
    const u16* __restrict__ srcp, const int* __restrict__ idxb,
    const u16* __restrict__ wb, const float* __restrict__ bias,
    u16* __restrict__ Xoutp) {
  __shared__ int nbrs[64];
  constexpr int CH = CIN / 2;
  constexpr int OPW = COUT / 4;
  constexpr int NAT = OPW / 16;

  const int t = threadIdx.x;
  const int b = blockIdx.z;
  const int p0 = blockIdx.x * 64;
  const int w = t >> 6, l = t & 63;
  const int quad = l >> 4, l15 = l & 15;
  const int cq8 = quad * 8;
  const int ow0 = w * OPW;

  if (t < 64) nbrs[t] = idxb[b * NKP + p0 + t] & (NN - 1);
  __syncthreads();

  int nbr[4], ctr[4];
  #pragma unroll
  for (int pg = 0; pg < 4; ++pg) {
    nbr[pg] = nbrs[pg * 16 + l15];
    ctr[pg] = blockIdx.x * 4 + pg;
  }

  f32x4 acc[NAT][4];
  #pragma unroll
  for (int i = 0; i < NAT; ++i)
    #pragma unroll
    for (int j = 0; j < 4; ++j) acc[i][j] = (f32x4)0.f;

  #pragma unroll 4
  for (int k = 0; k < CIN / 32; ++k) {
    short8 bfr[4];
    if (k * 32 < CH) {
      const int c = k * 32 + cq8;
      #pragma unroll
      for (int pg = 0; pg < 4; ++pg)
        bfr[pg] = *(const short8*)(srcp + ((size_t)(b * NN + nbr[pg]) * CH + c));
    } else {
      const int c = k * 32 + cq8 - CH;
      #pragma unroll
      for (int pg = 0; pg < 4; ++pg)
        bfr[pg] = *(const short8*)(srcp + ((size_t)(b * NN + ctr[pg]) * CH + c));
    }
    #pragma unroll
    for (int at = 0; at < NAT; ++at) {
      const short8 af = *(const short8*)(wb + ((size_t)(k * COUT + ow0 + at * 16 + l15)) * 32 + cq8);
      #pragma unroll
      for (int pg = 0; pg < 4; ++pg) acc[at][pg] = MFMA16(af, bfr[pg], acc[at][pg]);
    }
  }

  #pragma unroll
  for (int pg = 0; pg < 4; ++pg) {
    u16* orow = Xoutp + (size_t)(b * NN + ctr[pg]) * COUT + ow0;
    #pragma unroll
    for (int at = 0; at < NAT; ++at) {
      union { ushort4 v; u16 s[4]; } pk;
      #pragma unroll
      for (int r = 0; r < 4; ++r) {
        float v = lrelu(acc[at][pg][r] + bias[ow0 + at * 16 + quad * 4 + r]);
        v = fmaxf(v, __shfl_xor(v, 1));
        v = fmaxf(v, __shfl_xor(v, 2));
        v = fmaxf(v, __shfl_xor(v, 4));
        v = fmaxf(v, __shfl_xor(v, 8));
        pk.s[r] = f2bf(v);
      }
      if (l15 == 0) *(ushort4*)(orow + at * 16 + quad * 4) = pk.v;
    }
  }
}

// ---------------- conv5: barrier-free direct-fragment MFMA, partial max/sum ----------------
__global__ __launch_bounds__(256) void conv5_mfma(
    const u16* __restrict__ X1P, const u16* __restrict__ X2P,
    const u16* __restrict__ X3P, const u16* __restrict__ X4P,
    const u16* __restrict__ w5b, const float* __restrict__ b5,
    float* __restrict__ PMAX, float* __restrict__ PSUM) {
  const int t = threadIdx.x;
  const int b = blockIdx.z;
  const int n0 = blockIdx.x * 64;
  const int w = t >> 6, l = t & 63;
  const int quad = l >> 4, l15 = l & 15;
  const int cq8 = quad * 8;
  const int ow0 = blockIdx.y * 256 + w * 64;

  f32x4 acc[4][4];
  #pragma unroll
  for (int i = 0; i < 4; ++i)
    #pragma unroll
    for (int j = 0; j < 4; ++j) acc[i][j] = (f32x4)0.f;

  #pragma unroll 4
  for (int k = 0; k < 16; ++k) {
    const int c = k * 32 + cq8;
    short8 bfr[4];
    #pragma unroll
    for (int pg = 0; pg < 4; ++pg) {
      const int n = n0 + pg * 16 + l15;
      const u16* src; int cc;
      if (c < 64)       { src = X1P + (size_t)(b * NN + n) * 64;  cc = c; }
      else if (c < 128) { src = X2P + (size_t)(b * NN + n) * 64;  cc = c - 64; }
      else if (c < 256) { src = X3P + (size_t)(b * NN + n) * 128; cc = c - 128; }
      else              { src = X4P + (size_t)(b * NN + n) * 256; cc = c - 256; }
      bfr[pg] = *(const short8*)(src + cc);
    }
    #pragma unroll
    for (int at = 0; at < 4; ++at) {
      const short8 af = *(const short8*)(w5b + ((size_t)(k * 1024 + ow0 + at * 16 + l15)) * 32 + cq8);
      #pragma unroll
      for (int pg = 0; pg < 4; ++pg) acc[at][pg] = MFMA16(af, bfr[pg], acc[at][pg]);
    }
  }

  #pragma unroll
  for (int at = 0; at < 4; ++at) {
    f32x4 pmx, psm;
    #pragma unroll
    for (int r = 0; r < 4; ++r) {
      const float bb = b5[ow0 + at * 16 + quad * 4 + r];
      float m = -INFINITY, s = 0.f;
      #pragma unroll
      for (int pg = 0; pg < 4; ++pg) {
        const float v = lrelu(acc[at][pg][r] + bb);
        m = fmaxf(m, v); s += v;
      }
      #pragma unroll
      for (int msk = 1; msk < 16; msk <<= 1) {
        m = fmaxf(m, __shfl_xor(m, msk));
        s += __shfl_xor(s, msk);
      }
      pmx[r] = m; psm[r] = s;
    }
    if (l15 == 0) {
      float* dm = PMAX + (size_t)(b * 16 + blockIdx.x) * 1024 + ow0 + at * 16 + quad * 4;
      float* ds = PSUM + (size_t)(b * 16 + blockIdx.x) * 1024 + ow0 + at * 16 + quad * 4;
      *(f32x4*)dm = pmx;
      *(f32x4*)ds = psm;
    }
  }
}

__global__ __launch_bounds__(256) void reduce5(const float* __restrict__ PMAX, const float* __restrict__ PSUM,
                                               float* __restrict__ XPg) {
  const int tid = blockIdx.x * 256 + threadIdx.x;  // 8192
  const int b = tid >> 10, o = tid & 1023;
  float m = -INFINITY, s = 0.f;
  for (int pt = 0; pt < 16; ++pt) {
    m = fmaxf(m, PMAX[(size_t)(b * 16 + pt) * 1024 + o]);
    s += PSUM[(size_t)(b * 16 + pt) * 1024 + o];
  }
  XPg[b * 2048 + o] = m;
  XPg[b * 2048 + 1024 + o] = s * (1.f / 1024.f);
}

// ---------------- FC head ----------------
__global__ __launch_bounds__(256) void fc1_kernel(const float* __restrict__ XPg, const float* __restrict__ wl1t,
                                                  const float* __restrict__ bn4_b, float* __restrict__ XF1) {
  __shared__ float red[64 * 5];
  const int t = threadIdx.x;
  const int b = blockIdx.y;
  const int o = blockIdx.x * 64 + (t & 63);
  const int cq = t >> 6;
  const float* xp = XPg + b * 2048;
  float acc = 0.f;
  for (int c = cq * 512; c < cq * 512 + 512; ++c) acc = fmaf(wl1t[c * 512 + o], xp[c], acc);
  red[(t & 63) * 5 + cq] = acc;
  __syncthreads();
  if (t < 64) {
    const int oo = blockIdx.x * 64 + t;
    const float v = red[t * 5] + red[t * 5 + 1] + red[t * 5 + 2] + red[t * 5 + 3] + bn4_b[oo];
    XF1[b * 512 + oo] = lrelu(v);
  }
}

__global__ __launch_bounds__(256) void fc2_kernel(const float* __restrict__ XF1, const float* __restrict__ wl2t,
                                                  const float* __restrict__ bl2, const float* __restrict__ bn5_g,
                                                  const float* __restrict__ bn5_b, float* __restrict__ XF2) {
  __shared__ float red[64 * 5];
  const int t = threadIdx.x;
  const int b = blockIdx.y;
  const int o = blockIdx.x * 64 + (t & 63);
  const int cq = t >> 6;
  const float* xf = XF1 + b * 512;
  float acc = 0.f;
  for (int c = cq * 128; c < cq * 128 + 128; ++c) acc = fmaf(wl2t[c * 256 + o], xf[c], acc);
  red[(t & 63) * 5 + cq] = acc;
  __syncthreads();
  if (t < 64) {
    const int oo = blockIdx.x * 64 + t;
    const float bias = bl2[oo] * (bn5_g[oo] * BN_INV) + bn5_b[oo];
    const float v = red[t * 5] + red[t * 5 + 1] + red[t * 5 + 2] + red[t * 5 + 3] + bias;
    XF2[b * 256 + oo] = lrelu(v);
  }
}

__global__ __launch_bounds__(256) void fc3_kernel(const float* __restrict__ XF2, const float* __restrict__ wl3t,
                                                  const float* __restrict__ bl3, float* __restrict__ out) {
  __shared__ float red[64 * 5];
  const int t = threadIdx.x;
  const int b = blockIdx.y;
  const int ol = t & 63;
  const int cq = t >> 6;
  const float* xf = XF2 + b * 256;
  float acc = 0.f;
  if (ol < 49) for (int c = cq * 64; c < cq * 64 + 64; ++c) acc = fmaf(wl3t[c * 49 + ol], xf[c], acc);
  red[ol * 5 + cq] = acc;
  __syncthreads();
  if (t < 49) out[b * 49 + t] = red[t * 5] + red[t * 5 + 1] + red[t * 5 + 2] + red[t * 5 + 3] + bl3[t];
}

// ---------------- host ----------------
extern "C" void kernel_launch(void* const* d_in, const int* in_sizes, int n_in,
                              void* d_out, int out_size, void* d_ws, size_t ws_size,
                              hipStream_t stream) {
  (void)in_sizes; (void)n_in; (void)out_size; (void)ws_size;
  const float* x     = (const float*)d_in[0];
  const float* m1_w0 = (const float*)d_in[1];
  const float* m1_g0 = (const float*)d_in[2];
  const float* m1_b0 = (const float*)d_in[3];
  const float* m1_wm = (const float*)d_in[4];
  const float* m1_gm = (const float*)d_in[5];
  const float* m1_bm = (const float*)d_in[6];
  const float* m1_w1 = (const float*)d_in[7];
  const float* m1_go = (const float*)d_in[8];
  const float* m1_bo = (const float*)d_in[9];
  const float* m1_ws = (const float*)d_in[10];
  const float* m1_gs = (const float*)d_in[11];
  const float* m1_bs = (const float*)d_in[12];
  const float* m2_w0 = (const float*)d_in[13];
  const float* m2_g0 = (const float*)d_in[14];
  const float* m2_b0 = (const float*)d_in[15];
  const float* m2_wm = (const float*)d_in[16];
  const float* m2_gm = (const float*)d_in[17];
  const float* m2_bm = (const float*)d_in[18];
  const float* m2_w1 = (const float*)d_in[19];
  const float* m2_go = (const float*)d_in[20];
  const float* m2_bo = (const float*)d_in[21];
  const float* m2_ws = (const float*)d_in[22];
  const float* m2_gs = (const float*)d_in[23];
  const float* m2_bs = (const float*)d_in[24];
  const float* w3    = (const float*)d_in[25];
  const float* g3    = (const float*)d_in[26];
  const float* b3    = (const float*)d_in[27];
  const float* w4    = (const float*)d_in[28];
  const float* g4    = (const float*)d_in[29];
  const float* b4    = (const float*)d_in[30];
  const float* w5    = (const float*)d_in[31];
  const float* g5    = (const float*)d_in[32];
  const float* b5    = (const float*)d_in[33];
  const float* wl1   = (const float*)d_in[34];
  const float* bn4_g = (const float*)d_in[35];
  const float* bn4_b = (const float*)d_in[36];
  const float* wl2   = (const float*)d_in[37];
  const float* bl2   = (const float*)d_in[38];
  const float* bn5_g = (const float*)d_in[39];
  const float* bn5_b = (const float*)d_in[40];
  const float* wl3   = (const float*)d_in[41];
  const float* bl3   = (const float*)d_in[42];

  char* wsb = (char*)d_ws;
  int*  IDX  = (int*)(wsb + OFF_IDX);
  u16*  X1P  = (u16*)(wsb + OFF_X1P);
  u16*  X2P  = (u16*)(wsb + OFF_X2P);
  u16*  X3P  = (u16*)(wsb + OFF_X3P);
  u16*  X4P  = (u16*)(wsb + OFF_X4P);
  float* PMAX = (float*)(wsb + OFF_PMAX);
  float* PSUM = (float*)(wsb + OFF_PSUM);
  float* XPg  = (float*)(wsb + OFF_XP);
  float* XF1  = (float*)(wsb + OFF_XF1);
  float* XF2  = (float*)(wsb + OFF_XF2);
  u16*  M1W0 = (u16*)(wsb + OFF_M1W0);
  u16*  M1WM = (u16*)(wsb + OFF_M1WM);
  u16*  M1W1S = (u16*)(wsb + OFF_M1W1S);
  u16*  M2W0 = (u16*)(wsb + OFF_M2W0);
  u16*  M2WM = (u16*)(wsb + OFF_M2WM);
  u16*  M2W1S = (u16*)(wsb + OFF_M2W1S);
  u16*  W3B  = (u16*)(wsb + OFF_W3);
  u16*  W4B  = (u16*)(wsb + OFF_W4);
  u16*  W5B  = (u16*)(wsb + OFF_W5);
  float* WL1T = (float*)(wsb + OFF_WL1T);
  float* WL2T = (float*)(wsb + OFF_WL2T);
  float* WL3T = (float*)(wsb + OFF_WL3T);

  SArgs sa; int st = 0;
  auto sset = [&](int i, const float* w, const float* g, u16* dst, int O, int C, int cpl2, int ch) {
    sa.seg[i].w = w; sa.seg[i].g = g; sa.seg[i].dst = dst; sa.seg[i].O = O; sa.seg[i].C = C;
    sa.seg[i].cpl2 = cpl2; sa.seg[i].ch = ch; sa.seg[i].start = st; st += O << cpl2;
  };
  sset(0, m1_w0, m1_g0, M1W0, 64, 6, 5, 0);       // plain (B carries diffs)
  sset(1, m1_wm, m1_gm, M1WM, 64, 64, 6, 0);
  sset(2, m2_w0, m2_g0, M2W0, 64, 128, 7, 64);    // edge fold
  sset(3, m2_wm, m2_gm, M2WM, 64, 64, 6, 0);
  sset(4, w3, g3, W3B, 128, 128, 7, 64);          // edge fold
  sset(5, w4, g4, W4B, 256, 256, 8, 128);         // edge fold
  sset(6, w5, g5, W5B, 1024, 512, 9, 0);
  sa.total = st;

  TArgs3 ta; int tt = 0;
  auto tset = [&](int i, const float* w, const float* g, float* dst, int O, int C) {
    ta.seg[i].w = w; ta.seg[i].g = g; ta.seg[i].dst = dst; ta.seg[i].O = O; ta.seg[i].C = C;
    ta.seg[i].start = tt; tt += O * C;
  };
  tset(0, wl1, bn4_g, WL1T, 512, 2048);
  tset(1, wl2, bn5_g, WL2T, 256, 512);
  tset(2, wl3, nullptr, WL3T, 49, 256);
  ta.total = tt;

  hipLaunchKernelGGL(prep_scale_bf16, dim3((sa.total + 255) / 256), dim3(256), 0, stream, sa);
  hipLaunchKernelGGL(prep_w1s_bf16, dim3(104, 2), dim3(256), 0, stream,
                     m1_w1, m1_ws, m1_go, m1_gs, m2_w1, m2_ws, m2_go, m2_gs, M1W1S, M2W1S);
  hipLaunchKernelGGL(prep_transpose_f32, dim3((ta.total + 255) / 256), dim3(256), 0, stream, ta);

  hipLaunchKernelGGL(knn_kernel, dim3(2048), dim3(256), 0, stream, x, IDX);

  hipLaunchKernelGGL((mak_mfma<6>), dim3(256, 1, BB), dim3(256), 0, stream,
                     x, IDX, (const u16*)nullptr, M1W0, m1_b0, M1WM, m1_bm, M1W1S, m1_bo, m1_bs, X1P);
  hipLaunchKernelGGL((mak_mfma<128>), dim3(256, 1, BB), dim3(256), 0, stream,
                     x, IDX, X1P, M2W0, m2_b0, M2WM, m2_bm, M2W1S, m2_bo, m2_bs, X2P);

  hipLaunchKernelGGL((conv_maxk_mfma<128, 128>), dim3(256, 1, BB), dim3(256), 0, stream,
                     X2P, IDX, W3B, b3, X3P);
  hipLaunchKernelGGL((conv_maxk_mfma<256, 256>), dim3(256, 1, BB), dim3(256), 0, stream,
                     X3P, IDX, W4B, b4, X4P);

  hipLaunchKernelGGL(conv5_mfma, dim3(16, 4, BB), dim3(256), 0, stream,
                     X1P, X2P, X3P, X4P, W5B, b5, PMAX, PSUM);
  hipLaunchKernelGGL(reduce5, dim3(32), dim3(256), 0, stream, PMAX, PSUM, XPg);

  hipLaunchKernelGGL(fc1_kernel, dim3(8, BB), dim3(256), 0, stream, XPg, WL1T, bn4_b, XF1);
  hipLaunchKernelGGL(fc2_kernel, dim3(4, BB), dim3(256), 0, stream, XF1, WL2T, bl2, bn5_g, bn5_b, XF2);
  hipLaunchKernelGGL(fc3_kernel, dim3(1, BB), dim3(256), 0, stream, XF2, WL3T, bl3, (float*)d_out);
}

// Round 6
// 435.156 us; speedup vs baseline: 2.4600x; 1.0018x over previous
//
#include <hip/hip_runtime.h>
#include <math.h>

#define BB 8
#define NN 1024
#define KK 16
#define NKP (NN*KK)
#define BN_INV 0.99999500003749981f

typedef unsigned short u16;
typedef __attribute__((ext_vector_type(8))) short short8;
typedef __attribute__((ext_vector_type(4))) float f32x4;

#define MFMA16(a,b,c) __builtin_amdgcn_mfma_f32_16x16x32_bf16(a,b,c,0,0,0)

__device__ __forceinline__ float lrelu(float v) { return v >= 0.f ? v : 0.2f * v; }

__device__ __forceinline__ u16 f2bf(float f) {
  union { float f; unsigned u; } v; v.f = f;
  unsigned r = v.u + 0x7fff + ((v.u >> 16) & 1);
  return (u16)(r >> 16);
}
__device__ __forceinline__ float bf2f(u16 s) {
  union { unsigned u; float f; } v; v.u = ((unsigned)s) << 16;
  return v.f;
}

// ---------------- workspace byte offsets ----------------
constexpr size_t OFF_IDX   = 0;          // int[8*1024*16]
constexpr size_t OFF_X1P   = 524288;     // bf16 [8][1024][64]
constexpr size_t OFF_X2P   = 1572864;
constexpr size_t OFF_X3P   = 2621440;    // bf16 [8][1024][128]
constexpr size_t OFF_X4P   = 4718592;    // bf16 [8][1024][256]
constexpr size_t OFF_PMAX  = 8912896;    // f32 [8][16][1024]
constexpr size_t OFF_PSUM  = 9437184;
constexpr size_t OFF_XP    = 9961472;    // f32 [8][2048]
constexpr size_t OFF_XF1   = 10027008;   // f32 [8][512]
constexpr size_t OFF_XF2   = 10043392;   // f32 [8][256]
constexpr size_t OFF_M1W0  = 10051584;   // bf16 [1][64][32] (plain: B carries diffs)
constexpr size_t OFF_M1WM  = 10055680;   // bf16 [2][64][32]
constexpr size_t OFF_M1W1S = 10063872;   // bf16 [13][64][32]
constexpr size_t OFF_M2W0  = 10117120;   // bf16 [4][64][32] edge-folded [Wd|Wc-Wd]
constexpr size_t OFF_M2WM  = 10133504;   // bf16 [2][64][32]
constexpr size_t OFF_M2W1S = 10141696;   // bf16 [13][64][32]
constexpr size_t OFF_W3    = 10194944;   // bf16 [4][128][32] edge-folded
constexpr size_t OFF_W4    = 10227712;   // bf16 [8][256][32] edge-folded
constexpr size_t OFF_W5    = 10358784;   // bf16 [16][1024][32]
constexpr size_t OFF_WL1T  = 11407360;   // f32 [2048][512]
constexpr size_t OFF_WL2T  = 15601664;   // f32 [512][256]
constexpr size_t OFF_WL3T  = 16125952;   // f32 [256][49]

// ---------------- weight prep: chunk-major bf16 [C/32][O][32], gamma fold, optional edge fold ----------------
struct SSeg { const float* w; const float* g; u16* dst; int O; int C; int cpl2; int ch; int start; };
struct SArgs { SSeg seg[7]; int total; };

__global__ __launch_bounds__(256) void prep_scale_bf16(SArgs a) {
  const int tid = blockIdx.x * 256 + threadIdx.x;
  if (tid >= a.total) return;
  int s = 0;
  #pragma unroll
  for (int i = 1; i < 7; ++i) if (tid >= a.seg[i].start) s = i;
  const SSeg sg = a.seg[s];
  const int e = tid - sg.start;
  const int o = e >> sg.cpl2;
  const int c = e & ((1 << sg.cpl2) - 1);
  float v = 0.f;
  if (c < sg.C) {
    v = sg.w[o * sg.C + c];
    if (sg.ch && c >= sg.ch) v -= sg.w[o * sg.C + c - sg.ch];  // Wc - Wd (edge fold)
    v *= sg.g[o] * BN_INV;
  }
  sg.dst[(size_t)(c >> 5) * (sg.O * 32) + o * 32 + (c & 31)] = f2bf(v);
}

// w1s virtual-channel weights, chunk-major [13][64][32]
__global__ __launch_bounds__(256) void prep_w1s_bf16(
    const float* __restrict__ w1a, const float* __restrict__ wsa,
    const float* __restrict__ goa, const float* __restrict__ gsa,
    const float* __restrict__ w1b, const float* __restrict__ wsb,
    const float* __restrict__ gob, const float* __restrict__ gsb,
    u16* __restrict__ dsta, u16* __restrict__ dstb) {
  const int tid = blockIdx.x * 256 + threadIdx.x;
  if (tid >= 64 * 416) return;
  const float* w1 = blockIdx.y ? w1b : w1a;
  const float* wsm = blockIdx.y ? wsb : wsa;
  const float* go = blockIdx.y ? gob : goa;
  const float* gs = blockIdx.y ? gsb : gsa;
  u16* dst = blockIdx.y ? dstb : dsta;
  const int o = tid / 416, ci = tid - o * 416;
  float v = 0.f;
  if (ci < 384) {
    const int ii = ci >> 6, ch = ci & 63;
    const int base = (o * 24 + ii * 4) * 64 + ch;
    v = go[o] * BN_INV * (w1[base] + w1[base + 64] + w1[base + 128] + w1[base + 192]);
  } else if (ci < 390) {
    v = gs[o] * BN_INV * wsm[o * 6 + (ci - 384)];
  }
  dst[(size_t)(ci >> 5) * 2048 + o * 32 + (ci & 31)] = f2bf(v);
}

struct TSeg { const float* w; const float* g; float* dst; int O; int C; int start; };
struct TArgs3 { TSeg seg[3]; int total; };

__global__ __launch_bounds__(256) void prep_transpose_f32(TArgs3 a) {
  const int tid = blockIdx.x * 256 + threadIdx.x;
  if (tid >= a.total) return;
  int s = 0;
  #pragma unroll
  for (int i = 1; i < 3; ++i) if (tid >= a.seg[i].start) s = i;
  const TSeg sg = a.seg[s];
  const int e = tid - sg.start;
  const int c = e / sg.O;
  const int o = e - c * sg.O;
  float v = sg.w[o * sg.C + c];
  if (sg.g) v *= sg.g[o] * BN_INV;
  sg.dst[e] = v;
}

// ---------------- KNN (exact fp32) ----------------
__global__ __launch_bounds__(256) void knn_kernel(const float* __restrict__ x, int* __restrict__ idxout) {
  const int wid  = (blockIdx.x * blockDim.x + threadIdx.x) >> 6;
  const int lane = threadIdx.x & 63;
  const int b = wid >> 10;
  const int n = wid & (NN - 1);
  const float* xb = x + b * 3 * NN;
  const float x0n = xb[n], x1n = xb[NN + n], x2n = xb[2 * NN + n];
  const float xxn = x0n * x0n + x1n * x1n + x2n * x2n;
  float pd[16];
  #pragma unroll
  for (int j = 0; j < 16; ++j) {
    const int m = j * 64 + lane;
    const float x0 = xb[m], x1 = xb[NN + m], x2 = xb[2 * NN + m];
    const float dot = x0n * x0 + x1n * x1 + x2n * x2;
    const float xxm = x0 * x0 + x1 * x1 + x2 * x2;
    pd[j] = 2.f * dot - xxn - xxm;
  }
  for (int r = 0; r < 16; ++r) {
    float bv = pd[0]; int bj = 0;
    #pragma unroll
    for (int j = 1; j < 16; ++j) if (pd[j] > bv) { bv = pd[j]; bj = j; }
    int bm = bj * 64 + lane;
    #pragma unroll
    for (int off = 32; off > 0; off >>= 1) {
      const float ov = __shfl_down(bv, off);
      const int   om = __shfl_down(bm, off);
      if (ov > bv || (ov == bv && om < bm)) { bv = ov; bm = om; }
    }
    bm = __shfl(bm, 0);
    if (lane == 0) idxout[wid * KK + r] = bm;
    const int  cj   = bm >> 6;
    const bool mine = (bm & 63) == lane;
    #pragma unroll
    for (int j = 0; j < 16; ++j) if (mine && j == cj) pd[j] = -INFINITY;
  }
}

// ---------------- helpers ----------------
// swizzled [64p][64c] LDS tile: group g of row p at pos = g ^ (p&7)
__device__ __forceinline__ short8 bfrag64(const u16* T, int pl, int quad, int c0) {
  const int pos = ((c0 >> 3) + quad) ^ (pl & 7);
  return *(const short8*)(T + pl * 64 + pos * 8);
}
__device__ __forceinline__ void writeD64(u16* T, int pl, int quad, const f32x4 a,
                                         const float* __restrict__ bias, int obase) {
  union { ushort4 v; u16 s[4]; } pk;
  #pragma unroll
  for (int r = 0; r < 4; ++r) pk.s[r] = f2bf(lrelu(a[r] + bias[obase + quad * 4 + r]));
  const int g = (obase + quad * 4) >> 3;
  const int pos = g ^ (pl & 7);
  *(ushort4*)(T + pl * 64 + pos * 8 + (quad & 1) * 4) = pk.v;
}

// ---------------- fused mak block ----------------
// CIN_Y = 6 (m1: y = geo in regs, plain w0) or 128 (m2: raw x1p rows, edge-folded w0)
template<int CIN_Y>
__global__ __launch_bounds__(256) void mak_mfma(
    const float* __restrict__ x, const int* __restrict__ idxb, const u16* __restrict__ srcp,
    const u16* __restrict__ w0b, const float* __restrict__ b0v,
    const u16* __restrict__ wmb, const float* __restrict__ bmv,
    const u16* __restrict__ w1s, const float* __restrict__ bov, const float* __restrict__ bsv,
    u16* __restrict__ Xoutp) {
  __shared__ __align__(16) u16 Y0s[64 * 64];
  __shared__ __align__(16) u16 YMs[64 * 64];
  __shared__ int nbrs[64];

  const int t = threadIdx.x;
  const int b = blockIdx.z;
  const int p0 = blockIdx.x * 64;
  const int w = t >> 6, l = t & 63;
  const int quad = l >> 4, l15 = l & 15;
  const int pl = w * 16 + l15;
  const int cq8 = quad * 8;
  const int nvtx = blockIdx.x * 4 + w;   // center point of this wave's k-group

  if (t < 64) nbrs[t] = idxb[b * NKP + p0 + t] & (NN - 1);
  __syncthreads();
  const int nbr = nbrs[pl];

  // geo of point pl: fp32 coords -> fp32 diffs -> bf16
  const float* xb = x + b * 3 * NN;
  float ge[6];
  #pragma unroll
  for (int i = 0; i < 3; ++i) {
    const float fc = xb[i * NN + nvtx];
    ge[i]     = xb[i * NN + nbr] - fc;
    ge[3 + i] = fc;
  }
  union { short8 v; u16 s[8]; } bg;
  bg.v = (short8)(short)0;
  if (quad == 0) {
    #pragma unroll
    for (int j = 0; j < 6; ++j) bg.s[j] = f2bf(ge[j]);
  }

  f32x4 acc[4];
  #pragma unroll
  for (int i = 0; i < 4; ++i) acc[i] = (f32x4)0.f;

  // ---- GEMM1: y -> 64 ----
  if constexpr (CIN_Y == 6) {
    #pragma unroll
    for (int at = 0; at < 4; ++at) {
      const short8 af = *(const short8*)(w0b + (size_t)(at * 16 + l15) * 32 + cq8);
      acc[at] = MFMA16(af, bg.v, acc[at]);
    }
  } else {
    // prefetch all 4 B-frags (2 nbr + 2 ctr), then stream MFMAs
    short8 bf[4];
    #pragma unroll
    for (int k = 0; k < 2; ++k)
      bf[k] = *(const short8*)(srcp + (size_t)(b * NN + nbr) * 64 + k * 32 + cq8);
    #pragma unroll
    for (int k = 2; k < 4; ++k)
      bf[k] = *(const short8*)(srcp + (size_t)(b * NN + nvtx) * 64 + (k - 2) * 32 + cq8);
    #pragma unroll
    for (int k = 0; k < 4; ++k) {
      #pragma unroll
      for (int at = 0; at < 4; ++at) {
        const short8 af = *(const short8*)(w0b + (size_t)(k * 64 + at * 16 + l15) * 32 + cq8);
        acc[at] = MFMA16(af, bf[k], acc[at]);
      }
    }
  }
  #pragma unroll
  for (int at = 0; at < 4; ++at) writeD64(Y0s, pl, quad, acc[at], b0v, at * 16);
  __syncthreads();

  // ---- GEMM2: 64 -> 64 ----
  #pragma unroll
  for (int i = 0; i < 4; ++i) acc[i] = (f32x4)0.f;
  #pragma unroll
  for (int kc = 0; kc < 2; ++kc) {
    const short8 bf = bfrag64(Y0s, pl, quad, kc * 32);
    #pragma unroll
    for (int at = 0; at < 4; ++at) {
      const short8 af = *(const short8*)(wmb + (size_t)(kc * 64 + at * 16 + l15) * 32 + cq8);
      acc[at] = MFMA16(af, bf, acc[at]);
    }
  }
  #pragma unroll
  for (int at = 0; at < 4; ++at) writeD64(YMs, pl, quad, acc[at], bmv, at * 16);
  __syncthreads();

  // ---- GEMM3: 6 partial K=64 GEMMs, fp32 per-point multiplier post-MFMA ----
  #pragma unroll
  for (int i = 0; i < 4; ++i) acc[i] = (f32x4)0.f;
  #pragma unroll
  for (int ii = 0; ii < 6; ++ii) {
    f32x4 tacc[4];
    #pragma unroll
    for (int i = 0; i < 4; ++i) tacc[i] = (f32x4)0.f;
    #pragma unroll
    for (int kc = 0; kc < 2; ++kc) {
      const short8 bf = bfrag64(YMs, pl, quad, kc * 32);
      #pragma unroll
      for (int at = 0; at < 4; ++at) {
        const short8 af = *(const short8*)(w1s + (size_t)((ii * 2 + kc) * 64 + at * 16 + l15) * 32 + cq8);
        tacc[at] = MFMA16(af, bf, tacc[at]);
      }
    }
    const float g = ge[ii];
    #pragma unroll
    for (int at = 0; at < 4; ++at) acc[at] += g * tacc[at];
  }
  #pragma unroll
  for (int at = 0; at < 4; ++at) {   // idt chunk (k=12): B = geo fragment
    const short8 af = *(const short8*)(w1s + (size_t)(12 * 64 + at * 16 + l15) * 32 + cq8);
    acc[at] = MFMA16(af, bg.v, acc[at]);
  }

  // ---- epilogue: bias + lrelu, max over k=l15 ----
  u16* orow = Xoutp + (size_t)(b * NN + nvtx) * 64;
  #pragma unroll
  for (int at = 0; at < 4; ++at) {
    union { ushort4 v; u16 s[4]; } pk;
    #pragma unroll
    for (int r = 0; r < 4; ++r) {
      const int o = at * 16 + quad * 4 + r;
      float v = lrelu(acc[at][r] + bov[o] + bsv[o]);
      v = fmaxf(v, __shfl_xor(v, 1));
      v = fmaxf(v, __shfl_xor(v, 2));
      v = fmaxf(v, __shfl_xor(v, 4));
      v = fmaxf(v, __shfl_xor(v, 8));
      pk.s[r] = f2bf(v);
    }
    if (l15 == 0) *(ushort4*)(orow + at * 16 + quad * 4) = pk.v;
  }
}

// ---------------- edge conv: two-phase (prefetch-all-B, then MFMA stream) ----------------
template<int CIN, int COUT>
__global__ __launch_bounds__(256) void conv_maxk_mfma(
    const u16* __restrict__ srcp, const int* __restrict__ idxb,
    const u16* __restrict__ wb, const float* __restrict__ bias,
    u16* __restrict__ Xoutp) {
  __shared__ int nbrs[64];
  constexpr int CH = CIN / 2;
  constexpr int NCH = CIN / 32;   // total chunks
  constexpr int NHB = CH / 32;    // nbr chunks
  constexpr int OPW = COUT / 4;
  constexpr int NAT = OPW / 16;

  const int t = threadIdx.x;
  const int b = blockIdx.z;
  const int p0 = blockIdx.x * 64;
  const int w = t >> 6, l = t & 63;
  const int quad = l >> 4, l15 = l & 15;
  const int cq8 = quad * 8;
  const int ow0 = w * OPW;

  if (t < 64) nbrs[t] = idxb[b * NKP + p0 + t] & (NN - 1);
  __syncthreads();

  int nbr[4], ctr[4];
  #pragma unroll
  for (int pg = 0; pg < 4; ++pg) {
    nbr[pg] = nbrs[pg * 16 + l15];
    ctr[pg] = blockIdx.x * 4 + pg;
  }

  f32x4 acc[NAT][4];
  #pragma unroll
  for (int i = 0; i < NAT; ++i)
    #pragma unroll
    for (int j = 0; j < 4; ++j) acc[i][j] = (f32x4)0.f;

  // Phase 1: issue ALL B-fragment loads (one latency exposure, vmcnt-queued)
  short8 bfr[NCH][4];
  #pragma unroll
  for (int k = 0; k < NHB; ++k) {
    const int c = k * 32 + cq8;
    #pragma unroll
    for (int pg = 0; pg < 4; ++pg)
      bfr[k][pg] = *(const short8*)(srcp + ((size_t)(b * NN + nbr[pg]) * CH + c));
  }
  #pragma unroll
  for (int k = NHB; k < NCH; ++k) {
    const int c = (k - NHB) * 32 + cq8;
    #pragma unroll
    for (int pg = 0; pg < 4; ++pg)
      bfr[k][pg] = *(const short8*)(srcp + ((size_t)(b * NN + ctr[pg]) * CH + c));
  }

  // Phase 2: A-loads (L1-hot weights) + MFMA stream
  #pragma unroll
  for (int k = 0; k < NCH; ++k) {
    #pragma unroll
    for (int at = 0; at < NAT; ++at) {
      const short8 af = *(const short8*)(wb + ((size_t)(k * COUT + ow0 + at * 16 + l15)) * 32 + cq8);
      #pragma unroll
      for (int pg = 0; pg < 4; ++pg) acc[at][pg] = MFMA16(af, bfr[k][pg], acc[at][pg]);
    }
  }

  #pragma unroll
  for (int pg = 0; pg < 4; ++pg) {
    u16* orow = Xoutp + (size_t)(b * NN + ctr[pg]) * COUT + ow0;
    #pragma unroll
    for (int at = 0; at < NAT; ++at) {
      union { ushort4 v; u16 s[4]; } pk;
      #pragma unroll
      for (int r = 0; r < 4; ++r) {
        float v = lrelu(acc[at][pg][r] + bias[ow0 + at * 16 + quad * 4 + r]);
        v = fmaxf(v, __shfl_xor(v, 1));
        v = fmaxf(v, __shfl_xor(v, 2));
        v = fmaxf(v, __shfl_xor(v, 4));
        v = fmaxf(v, __shfl_xor(v, 8));
        pk.s[r] = f2bf(v);
      }
      if (l15 == 0) *(ushort4*)(orow + at * 16 + quad * 4) = pk.v;
    }
  }
}

// ---------------- conv5: barrier-free direct-fragment MFMA, partial max/sum ----------------
__global__ __launch_bounds__(256) void conv5_mfma(
    const u16* __restrict__ X1P, const u16* __restrict__ X2P,
    const u16* __restrict__ X3P, const u16* __restrict__ X4P,
    const u16* __restrict__ w5b, const float* __restrict__ b5,
    float* __restrict__ PMAX, float* __restrict__ PSUM) {
  const int t = threadIdx.x;
  const int b = blockIdx.z;
  const int n0 = blockIdx.x * 64;
  const int w = t >> 6, l = t & 63;
  const int quad = l >> 4, l15 = l & 15;
  const int cq8 = quad * 8;
  const int ow0 = blockIdx.y * 256 + w * 64;

  f32x4 acc[4][4];
  #pragma unroll
  for (int i = 0; i < 4; ++i)
    #pragma unroll
    for (int j = 0; j < 4; ++j) acc[i][j] = (f32x4)0.f;

  #pragma unroll 4
  for (int k = 0; k < 16; ++k) {
    const int c = k * 32 + cq8;
    short8 bfr[4];
    #pragma unroll
    for (int pg = 0; pg < 4; ++pg) {
      const int n = n0 + pg * 16 + l15;
      const u16* src; int cc;
      if (c < 64)       { src = X1P + (size_t)(b * NN + n) * 64;  cc = c; }
      else if (c < 128) { src = X2P + (size_t)(b * NN + n) * 64;  cc = c - 64; }
      else if (c < 256) { src = X3P + (size_t)(b * NN + n) * 128; cc = c - 128; }
      else              { src = X4P + (size_t)(b * NN + n) * 256; cc = c - 256; }
      bfr[pg] = *(const short8*)(src + cc);
    }
    #pragma unroll
    for (int at = 0; at < 4; ++at) {
      const short8 af = *(const short8*)(w5b + ((size_t)(k * 1024 + ow0 + at * 16 + l15)) * 32 + cq8);
      #pragma unroll
      for (int pg = 0; pg < 4; ++pg) acc[at][pg] = MFMA16(af, bfr[pg], acc[at][pg]);
    }
  }

  #pragma unroll
  for (int at = 0; at < 4; ++at) {
    f32x4 pmx, psm;
    #pragma unroll
    for (int r = 0; r < 4; ++r) {
      const float bb = b5[ow0 + at * 16 + quad * 4 + r];
      float m = -INFINITY, s = 0.f;
      #pragma unroll
      for (int pg = 0; pg < 4; ++pg) {
        const float v = lrelu(acc[at][pg][r] + bb);
        m = fmaxf(m, v); s += v;
      }
      #pragma unroll
      for (int msk = 1; msk < 16; msk <<= 1) {
        m = fmaxf(m, __shfl_xor(m, msk));
        s += __shfl_xor(s, msk);
      }
      pmx[r] = m; psm[r] = s;
    }
    if (l15 == 0) {
      float* dm = PMAX + (size_t)(b * 16 + blockIdx.x) * 1024 + ow0 + at * 16 + quad * 4;
      float* ds = PSUM + (size_t)(b * 16 + blockIdx.x) * 1024 + ow0 + at * 16 + quad * 4;
      *(f32x4*)dm = pmx;
      *(f32x4*)ds = psm;
    }
  }
}

__global__ __launch_bounds__(256) void reduce5(const float* __restrict__ PMAX, const float* __restrict__ PSUM,
                                               float* __restrict__ XPg) {
  const int tid = blockIdx.x * 256 + threadIdx.x;  // 8192
  const int b = tid >> 10, o = tid & 1023;
  float m = -INFINITY, s = 0.f;
  for (int pt = 0; pt < 16; ++pt) {
    m = fmaxf(m, PMAX[(size_t)(b * 16 + pt) * 1024 + o]);
    s += PSUM[(size_t)(b * 16 + pt) * 1024 + o];
  }
  XPg[b * 2048 + o] = m;
  XPg[b * 2048 + 1024 + o] = s * (1.f / 1024.f);
}

// ---------------- FC head ----------------
__global__ __launch_bounds__(256) void fc1_kernel(const float* __restrict__ XPg, const float* __restrict__ wl1t,
                                                  const float* __restrict__ bn4_b, float* __restrict__ XF1) {
  __shared__ float red[64 * 5];
  const int t = threadIdx.x;
  const int b = blockIdx.y;
  const int o = blockIdx.x * 64 + (t & 63);
  const int cq = t >> 6;
  const float* xp = XPg + b * 2048;
  float acc = 0.f;
  for (int c = cq * 512; c < cq * 512 + 512; ++c) acc = fmaf(wl1t[c * 512 + o], xp[c], acc);
  red[(t & 63) * 5 + cq] = acc;
  __syncthreads();
  if (t < 64) {
    const int oo = blockIdx.x * 64 + t;
    const float v = red[t * 5] + red[t * 5 + 1] + red[t * 5 + 2] + red[t * 5 + 3] + bn4_b[oo];
    XF1[b * 512 + oo] = lrelu(v);
  }
}

__global__ __launch_bounds__(256) void fc2_kernel(const float* __restrict__ XF1, const float* __restrict__ wl2t,
                                                  const float* __restrict__ bl2, const float* __restrict__ bn5_g,
                                                  const float* __restrict__ bn5_b, float* __restrict__ XF2) {
  __shared__ float red[64 * 5];
  const int t = threadIdx.x;
  const int b = blockIdx.y;
  const int o = blockIdx.x * 64 + (t & 63);
  const int cq = t >> 6;
  const float* xf = XF1 + b * 512;
  float acc = 0.f;
  for (int c = cq * 128; c < cq * 128 + 128; ++c) acc = fmaf(wl2t[c * 256 + o], xf[c], acc);
  red[(t & 63) * 5 + cq] = acc;
  __syncthreads();
  if (t < 64) {
    const int oo = blockIdx.x * 64 + t;
    const float bias = bl2[oo] * (bn5_g[oo] * BN_INV) + bn5_b[oo];
    const float v = red[t * 5] + red[t * 5 + 1] + red[t * 5 + 2] + red[t * 5 + 3] + bias;
    XF2[b * 256 + oo] = lrelu(v);
  }
}

__global__ __launch_bounds__(256) void fc3_kernel(const float* __restrict__ XF2, const float* __restrict__ wl3t,
                                                  const float* __restrict__ bl3, float* __restrict__ out) {
  __shared__ float red[64 * 5];
  const int t = threadIdx.x;
  const int b = blockIdx.y;
  const int ol = t & 63;
  const int cq = t >> 6;
  const float* xf = XF2 + b * 256;
  float acc = 0.f;
  if (ol < 49) for (int c = cq * 64; c < cq * 64 + 64; ++c) acc = fmaf(wl3t[c * 49 + ol], xf[c], acc);
  red[ol * 5 + cq] = acc;
  __syncthreads();
  if (t < 49) out[b * 49 + t] = red[t * 5] + red[t * 5 + 1] + red[t * 5 + 2] + red[t * 5 + 3] + bl3[t];
}

// ---------------- host ----------------
extern "C" void kernel_launch(void* const* d_in, const int* in_sizes, int n_in,
                              void* d_out, int out_size, void* d_ws, size_t ws_size,
                              hipStream_t stream) {
  (void)in_sizes; (void)n_in; (void)out_size; (void)ws_size;
  const float* x     = (const float*)d_in[0];
  const float* m1_w0 = (const float*)d_in[1];
  const float* m1_g0 = (const float*)d_in[2];
  const float* m1_b0 = (const float*)d_in[3];
  const float* m1_wm = (const float*)d_in[4];
  const float* m1_gm = (const float*)d_in[5];
  const float* m1_bm = (const float*)d_in[6];
  const float* m1_w1 = (const float*)d_in[7];
  const float* m1_go = (const float*)d_in[8];
  const float* m1_bo = (const float*)d_in[9];
  const float* m1_ws = (const float*)d_in[10];
  const float* m1_gs = (const float*)d_in[11];
  const float* m1_bs = (const float*)d_in[12];
  const float* m2_w0 = (const float*)d_in[13];
  const float* m2_g0 = (const float*)d_in[14];
  const float* m2_b0 = (const float*)d_in[15];
  const float* m2_wm = (const float*)d_in[16];
  const float* m2_gm = (const float*)d_in[17];
  const float* m2_bm = (const float*)d_in[18];
  const float* m2_w1 = (const float*)d_in[19];
  const float* m2_go = (const float*)d_in[20];
  const float* m2_bo = (const float*)d_in[21];
  const float* m2_ws = (const float*)d_in[22];
  const float* m2_gs = (const float*)d_in[23];
  const float* m2_bs = (const float*)d_in[24];
  const float* w3    = (const float*)d_in[25];
  const float* g3    = (const float*)d_in[26];
  const float* b3    = (const float*)d_in[27];
  const float* w4    = (const float*)d_in[28];
  const float* g4    = (const float*)d_in[29];
  const float* b4    = (const float*)d_in[30];
  const float* w5    = (const float*)d_in[31];
  const float* g5    = (const float*)d_in[32];
  const float* b5    = (const float*)d_in[33];
  const float* wl1   = (const float*)d_in[34];
  const float* bn4_g = (const float*)d_in[35];
  const float* bn4_b = (const float*)d_in[36];
  const float* wl2   = (const float*)d_in[37];
  const float* bl2   = (const float*)d_in[38];
  const float* bn5_g = (const float*)d_in[39];
  const float* bn5_b = (const float*)d_in[40];
  const float* wl3   = (const float*)d_in[41];
  const float* bl3   = (const float*)d_in[42];

  char* wsb = (char*)d_ws;
  int*  IDX  = (int*)(wsb + OFF_IDX);
  u16*  X1P  = (u16*)(wsb + OFF_X1P);
  u16*  X2P  = (u16*)(wsb + OFF_X2P);
  u16*  X3P  = (u16*)(wsb + OFF_X3P);
  u16*  X4P  = (u16*)(wsb + OFF_X4P);
  float* PMAX = (float*)(wsb + OFF_PMAX);
  float* PSUM = (float*)(wsb + OFF_PSUM);
  float* XPg  = (float*)(wsb + OFF_XP);
  float* XF1  = (float*)(wsb + OFF_XF1);
  float* XF2  = (float*)(wsb + OFF_XF2);
  u16*  M1W0 = (u16*)(wsb + OFF_M1W0);
  u16*  M1WM = (u16*)(wsb + OFF_M1WM);
  u16*  M1W1S = (u16*)(wsb + OFF_M1W1S);
  u16*  M2W0 = (u16*)(wsb + OFF_M2W0);
  u16*  M2WM = (u16*)(wsb + OFF_M2WM);
  u16*  M2W1S = (u16*)(wsb + OFF_M2W1S);
  u16*  W3B  = (u16*)(wsb + OFF_W3);
  u16*  W4B  = (u16*)(wsb + OFF_W4);
  u16*  W5B  = (u16*)(wsb + OFF_W5);
  float* WL1T = (float*)(wsb + OFF_WL1T);
  float* WL2T = (float*)(wsb + OFF_WL2T);
  float* WL3T = (float*)(wsb + OFF_WL3T);

  SArgs sa; int st = 0;
  auto sset = [&](int i, const float* w, const float* g, u16* dst, int O, int C, int cpl2, int ch) {
    sa.seg[i].w = w; sa.seg[i].g = g; sa.seg[i].dst = dst; sa.seg[i].O = O; sa.seg[i].C = C;
    sa.seg[i].cpl2 = cpl2; sa.seg[i].ch = ch; sa.seg[i].start = st; st += O << cpl2;
  };
  sset(0, m1_w0, m1_g0, M1W0, 64, 6, 5, 0);       // plain (B carries diffs)
  sset(1, m1_wm, m1_gm, M1WM, 64, 64, 6, 0);
  sset(2, m2_w0, m2_g0, M2W0, 64, 128, 7, 64);    // edge fold
  sset(3, m2_wm, m2_gm, M2WM, 64, 64, 6, 0);
  sset(4, w3, g3, W3B, 128, 128, 7, 64);          // edge fold
  sset(5, w4, g4, W4B, 256, 256, 8, 128);         // edge fold
  sset(6, w5, g5, W5B, 1024, 512, 9, 0);
  sa.total = st;

  TArgs3 ta; int tt = 0;
  auto tset = [&](int i, const float* w, const float* g, float* dst, int O, int C) {
    ta.seg[i].w = w; ta.seg[i].g = g; ta.seg[i].dst = dst; ta.seg[i].O = O; ta.seg[i].C = C;
    ta.seg[i].start = tt; tt += O * C;
  };
  tset(0, wl1, bn4_g, WL1T, 512, 2048);
  tset(1, wl2, bn5_g, WL2T, 256, 512);
  tset(2, wl3, nullptr, WL3T, 49, 256);
  ta.total = tt;

  hipLaunchKernelGGL(prep_scale_bf16, dim3((sa.total + 255) / 256), dim3(256), 0, stream, sa);
  hipLaunchKernelGGL(prep_w1s_bf16, dim3(104, 2), dim3(256), 0, stream,
                     m1_w1, m1_ws, m1_go, m1_gs, m2_w1, m2_ws, m2_go, m2_gs, M1W1S, M2W1S);
  hipLaunchKernelGGL(prep_transpose_f32, dim3((ta.total + 255) / 256), dim3(256), 0, stream, ta);

  hipLaunchKernelGGL(knn_kernel, dim3(2048), dim3(256), 0, stream, x, IDX);

  hipLaunchKernelGGL((mak_mfma<6>), dim3(256, 1, BB), dim3(256), 0, stream,
                     x, IDX, (const u16*)nullptr, M1W0, m1_b0, M1WM, m1_bm, M1W1S, m1_bo, m1_bs, X1P);
  hipLaunchKernelGGL((mak_mfma<128>), dim3(256, 1, BB), dim3(256), 0, stream,
                     x, IDX, X1P, M2W0, m2_b0, M2WM, m2_bm, M2W1S, m2_bo, m2_bs, X2P);

  hipLaunchKernelGGL((conv_maxk_mfma<128, 128>), dim3(256, 1, BB), dim3(256), 0, stream,
                     X2P, IDX, W3B, b3, X3P);
  hipLaunchKernelGGL((conv_maxk_mfma<256, 256>), dim3(256, 1, BB), dim3(256), 0, stream,
                     X3P, IDX, W4B, b4, X4P);

  hipLaunchKernelGGL(conv5_mfma, dim3(16, 4, BB), dim3(256), 0, stream,
                     X1P, X2P, X3P, X4P, W5B, b5, PMAX, PSUM);
  hipLaunchKernelGGL(reduce5, dim3(32), dim3(256), 0, stream, PMAX, PSUM, XPg);

  hipLaunchKernelGGL(fc1_kernel, dim3(8, BB), dim3(256), 0, stream, XPg, WL1T, bn4_b, XF1);
  hipLaunchKernelGGL(fc2_kernel, dim3(4, BB), dim3(256), 0, stream, XF1, WL2T, bl2, bn5_g, bn5_b, XF2);
  hipLaunchKernelGGL(fc3_kernel, dim3(1, BB), dim3(256), 0, stream, XF2, WL3T, bl3, (float*)d_out);
}